// Round 12
// baseline (823.669 us; speedup 1.0000x reference)
//
#include <hip/hip_runtime.h>
#include <hip/hip_bf16.h>
#include <math.h>

#define N_NODES 50000
#define N_EDGES 800000
#define NUM_GRAPHS 500
#define F_IN 128
#define HID 256
#define NCLS 10

typedef _Float16 f16;
typedef _Float16 f16x8 __attribute__((ext_vector_type(8)));
typedef _Float16 f16x4 __attribute__((ext_vector_type(4)));
typedef float f32x4 __attribute__((ext_vector_type(4)));

#define LOW40 ((1ULL << 40) - 1)

// async global->LDS, 16B per lane, wave-uniform LDS base + lane*16
#define GL16(gp, lp)                                                        \
  __builtin_amdgcn_global_load_lds(                                         \
      (const __attribute__((address_space(1))) unsigned int*)(unsigned long long)(gp), \
      (__attribute__((address_space(3))) unsigned int*)(unsigned int)(unsigned long long)(lp), \
      16, 0, 0)

// ---------------- fp32 -> (hi,lo) f16 split, elementwise (float4/thread) ------
__global__ __launch_bounds__(256) void split_f32(const float* __restrict__ in,
                                                 f16* __restrict__ hi,
                                                 f16* __restrict__ lo, int n4) {
  int i = blockIdx.x * 256 + threadIdx.x;
  if (i < n4) {
    float4 v = ((const float4*)in)[i];
    f16x4 h, l;
    f16 h0 = (f16)v.x; h[0] = h0; l[0] = (f16)(v.x - (float)h0);
    f16 h1 = (f16)v.y; h[1] = h1; l[1] = (f16)(v.y - (float)h1);
    f16 h2 = (f16)v.z; h[2] = h2; l[2] = (f16)(v.z - (float)h2);
    f16 h3 = (f16)v.w; h[3] = h3; l[3] = (f16)(v.w - (float)h3);
    ((f16x4*)hi)[i] = h;
    ((f16x4*)lo)[i] = l;
  }
}

// -------- weight transpose + split: W[b][K][Mc] -> T[b][Mc][K] (hi,lo) --------
__global__ __launch_bounds__(256) void tsplit(const float* __restrict__ W,
                                              f16* __restrict__ Th,
                                              f16* __restrict__ Tl,
                                              int K, int Mc, int total) {
  int tid = blockIdx.x * 256 + threadIdx.x;
  if (tid < total) {
    int km = K * Mc;
    int b = tid / km;
    int rem = tid - b * km;
    int m = rem / K;
    int k = rem - m * K;
    float v = W[(size_t)b * km + (size_t)k * Mc + m];
    f16 h = (f16)v;
    Th[tid] = h;
    Tl[tid] = (f16)(v - (float)h);
  }
}

// ---------------- MFMA GEMM (f16x2 emulation), async dbuf LDS ---------------
// C = (Ah+Al)@(Bh+Bl) ~ ah*bh + ah*bl + al*bh ; Bt transposed [Nc][K].
// 4 waves (2x2), tile 128x128, BK=32. LDS fragment-order [kchunk4][row128][8f16]
// per plane; 2 buffers x 4 planes x 8KB = 64KB. global_load_lds staging (no
// VGPR round-trip), loads for step t+1 issued before MFMA of step t, ONE
// barrier per k-step (m97 structure).
__global__ __launch_bounds__(256) void gemm_mfma(
    const f16* __restrict__ Ah, const f16* __restrict__ Al,
    const f16* __restrict__ Bth, const f16* __restrict__ Btl,
    const float* __restrict__ bias,
    f16* __restrict__ Ch, f16* __restrict__ Cl,
    int M, int K, int Nc) {
  __shared__ f16 S[2][4][4096];
  const int t = threadIdx.x;
  const int lane = t & 63;
  const int wave = t >> 6;
  const int wm = wave >> 1, wn = wave & 1;
  const int brow0 = blockIdx.x * 128, bcol0 = blockIdx.y * 128;
  const int row0 = brow0 + wm * 64, col0 = bcol0 + wn * 64;
  const int lr = lane & 15;
  const int kc = lane >> 4;  // kchunk 0..3

  f32x4 acc[4][4];
  const f32x4 vzero = {0.f, 0.f, 0.f, 0.f};
#pragma unroll
  for (int m = 0; m < 4; ++m)
#pragma unroll
    for (int n = 0; n < 4; ++n) acc[m][n] = vzero;

  // staging: wave w stages plane w (0=Ah,1=Al,2=Bth,3=Btl)
  const f16* P = (wave == 0) ? Ah : (wave == 1) ? Al : (wave == 2) ? Bth : Btl;
  const int Rb = (wave < 2) ? brow0 : bcol0;
  int srow0 = Rb + lane;
  int srow1 = Rb + 64 + lane;
  if (wave < 2) {  // A-plane M tail: clamp (dup rows; C writes guarded)
    if (srow0 > M - 1) srow0 = M - 1;
    if (srow1 > M - 1) srow1 = M - 1;
  }
  const size_t g0 = (size_t)srow0 * K;
  const size_t g1 = (size_t)srow1 * K;

  const int T = K >> 5;
#pragma unroll 1
  for (int tt = -1; tt < T; ++tt) {
    // issue async loads for k-step tt+1 into buffer (tt+1)&1
    if (tt + 1 < T) {
      const int k0 = (tt + 1) << 5;
      f16* L = &S[(tt + 1) & 1][wave][0];
#pragma unroll
      for (int c = 0; c < 4; ++c) {
        GL16(P + g0 + k0 + c * 8, L + c * 1024);
        GL16(P + g1 + k0 + c * 8, L + c * 1024 + 512);
      }
    }
    if (tt >= 0) {
      // fragments from LDS (conflict-free: lanes 0-15 read 16 consecutive 16B)
      const int cur = tt & 1;
      f16x8 ah[4], al[4], bh[4], bl[4];
#pragma unroll
      for (int m = 0; m < 4; ++m) {
        int o = kc * 1024 + (wm * 64 + m * 16 + lr) * 8;
        ah[m] = *(const f16x8*)(&S[cur][0][o]);
        al[m] = *(const f16x8*)(&S[cur][1][o]);
      }
#pragma unroll
      for (int n = 0; n < 4; ++n) {
        int o = kc * 1024 + (wn * 64 + n * 16 + lr) * 8;
        bh[n] = *(const f16x8*)(&S[cur][2][o]);
        bl[n] = *(const f16x8*)(&S[cur][3][o]);
      }
#pragma unroll
      for (int m = 0; m < 4; ++m)
#pragma unroll
        for (int n = 0; n < 4; ++n) {
          acc[m][n] = __builtin_amdgcn_mfma_f32_16x16x32_f16(ah[m], bh[n], acc[m][n], 0, 0, 0);
          acc[m][n] = __builtin_amdgcn_mfma_f32_16x16x32_f16(ah[m], bl[n], acc[m][n], 0, 0, 0);
          acc[m][n] = __builtin_amdgcn_mfma_f32_16x16x32_f16(al[m], bh[n], acc[m][n], 0, 0, 0);
        }
    }
    __syncthreads();  // drains vmcnt (next-tile loads) + orders LDS reuse
  }

  const int rbase = (lane >> 4) * 4;
#pragma unroll
  for (int m = 0; m < 4; ++m) {
#pragma unroll
    for (int r = 0; r < 4; ++r) {
      int row = row0 + m * 16 + rbase + r;
      if (row < M) {
#pragma unroll
        for (int n = 0; n < 4; ++n) {
          int col = col0 + n * 16 + lr;
          float v = acc[m][n][r];
          if (bias) v += bias[col];
          f16 h = (f16)v;
          size_t o = (size_t)row * Nc + col;
          Ch[o] = h;
          Cl[o] = (f16)(v - (float)h);
        }
      }
    }
  }
}

// ------- degree accumulation: ONE packed u64 atomic per edge ----------------
__global__ __launch_bounds__(256) void deg_accum(
    const int* __restrict__ dst, const float* __restrict__ ew,
    unsigned long long* __restrict__ dpack, int E) {
  int e = blockIdx.x * 256 + threadIdx.x;
  if (e < E) {
    unsigned long long v = (1ULL << 40) |
        (unsigned long long)(unsigned)(ew[e] * 16777216.0f + 0.5f);
    atomicAdd(&dpack[dst[e]], v);
  }
}

// ---------------- hierarchical exclusive scan + dinv (from packed) -----------
__global__ __launch_bounds__(256) void scan_p1(
    const unsigned long long* __restrict__ dpack,
    float* __restrict__ dinv, int* __restrict__ bsum, int n) {
  __shared__ int s[256];
  int i = blockIdx.x * 256 + threadIdx.x;
  int c = 0;
  if (i < n) {
    unsigned long long v = dpack[i];
    c = (int)(v >> 40);
    float d = (float)(v & LOW40) * (1.0f / 16777216.0f);
    dinv[i] = rsqrtf(d + 1.0f);
  }
  s[threadIdx.x] = c;
  __syncthreads();
  for (int off = 128; off > 0; off >>= 1) {
    if (threadIdx.x < off) s[threadIdx.x] += s[threadIdx.x + off];
    __syncthreads();
  }
  if (threadIdx.x == 0) bsum[blockIdx.x] = s[0];
}

__global__ __launch_bounds__(256) void scan_p2(int* __restrict__ bsum, int nb,
                                               int* __restrict__ total_out) {
  __shared__ int s[256];
  int t = threadIdx.x;
  int v = (t < nb) ? bsum[t] : 0;
  s[t] = v;
  __syncthreads();
  for (int off = 1; off < 256; off <<= 1) {
    int u = (t >= off) ? s[t - off] : 0;
    __syncthreads();
    s[t] += u;
    __syncthreads();
  }
  if (t < nb) bsum[t] = s[t] - v;
  if (t == 255) *total_out = s[255];
}

__global__ __launch_bounds__(256) void scan_p3(
    const unsigned long long* __restrict__ dpack,
    const int* __restrict__ bsum, int* __restrict__ row_ptr, int n) {
  __shared__ int s[256];
  int i = blockIdx.x * 256 + threadIdx.x;
  int t = threadIdx.x;
  int v = (i < n) ? (int)(dpack[i] >> 40) : 0;
  s[t] = v;
  __syncthreads();
  for (int off = 1; off < 256; off <<= 1) {
    int u = (t >= off) ? s[t - off] : 0;
    __syncthreads();
    s[t] += u;
    __syncthreads();
  }
  if (i < n) row_ptr[i] = bsum[blockIdx.x] + s[t] - v;
}

// ---------------- CSR fill ----------------
__global__ __launch_bounds__(256) void csr_fill(
    const int* __restrict__ src, const int* __restrict__ dst,
    const float* __restrict__ ew, const float* __restrict__ dinv,
    const int* __restrict__ row_ptr, int* cursor,
    int* __restrict__ csr_src, float* __restrict__ csr_coef, int E) {
  int e = blockIdx.x * 256 + threadIdx.x;
  if (e < E) {
    int s = src[e], d = dst[e];
    int pos = atomicAdd(&cursor[d], 1);
    int idx = row_ptr[d] + pos;
    csr_src[idx] = s;
    csr_coef[idx] = dinv[s] * ew[e] * dinv[d];
  }
}

// -- aggregation + bias + ELU: neighbors read HI PLANE ONLY (halves traffic) --
__global__ __launch_bounds__(256) void gather_elu(
    const f16* __restrict__ Hh, const f16* __restrict__ Hl,
    const float* __restrict__ dinv, const int* __restrict__ row_ptr,
    const int* __restrict__ csr_src, const float* __restrict__ csr_coef,
    const float* __restrict__ bias,
    f16* __restrict__ Oh, f16* __restrict__ Ol) {
  const int wave = threadIdx.x >> 6;
  const int lane = threadIdx.x & 63;
  const int n = blockIdx.x * 4 + wave;
  if (n >= N_NODES) return;
  const f16x4* hh4 = (const f16x4*)Hh;
  const int start = row_ptr[n], end = row_ptr[n + 1];
  const float di = dinv[n];
  const float cself = di * di;
  size_t self = (size_t)n * 64 + lane;
  f16x4 sh = hh4[self];
  f16x4 sl = ((const f16x4*)Hl)[self];
  float a0 = cself * ((float)sh[0] + (float)sl[0]);
  float a1 = cself * ((float)sh[1] + (float)sl[1]);
  float a2 = cself * ((float)sh[2] + (float)sl[2]);
  float a3 = cself * ((float)sh[3] + (float)sl[3]);
  const int npairs = (end - start) >> 1;
  int e = start;
  if (npairs > 0) {
    int s0 = csr_src[e], s1 = csr_src[e + 1];
    float w0 = csr_coef[e], w1 = csr_coef[e + 1];
    for (int p = 1; p < npairs; ++p) {
      e += 2;
      f16x4 v0 = hh4[(size_t)s0 * 64 + lane];
      f16x4 v1 = hh4[(size_t)s1 * 64 + lane];
      int t0 = csr_src[e], t1 = csr_src[e + 1];
      float u0 = csr_coef[e], u1 = csr_coef[e + 1];
      a0 += w0 * (float)v0[0] + w1 * (float)v1[0];
      a1 += w0 * (float)v0[1] + w1 * (float)v1[1];
      a2 += w0 * (float)v0[2] + w1 * (float)v1[2];
      a3 += w0 * (float)v0[3] + w1 * (float)v1[3];
      s0 = t0; s1 = t1; w0 = u0; w1 = u1;
    }
    f16x4 v0 = hh4[(size_t)s0 * 64 + lane];
    f16x4 v1 = hh4[(size_t)s1 * 64 + lane];
    a0 += w0 * (float)v0[0] + w1 * (float)v1[0];
    a1 += w0 * (float)v0[1] + w1 * (float)v1[1];
    a2 += w0 * (float)v0[2] + w1 * (float)v1[2];
    a3 += w0 * (float)v0[3] + w1 * (float)v1[3];
    e += 2;
  }
  if (e < end) {
    int s0 = csr_src[e];
    float w0 = csr_coef[e];
    f16x4 v0 = hh4[(size_t)s0 * 64 + lane];
    a0 += w0 * (float)v0[0];
    a1 += w0 * (float)v0[1];
    a2 += w0 * (float)v0[2];
    a3 += w0 * (float)v0[3];
  }
  float4 bb = ((const float4*)bias)[lane];
  a0 += bb.x; a1 += bb.y; a2 += bb.z; a3 += bb.w;
  a0 = (a0 > 0.f) ? a0 : expm1f(a0);
  a1 = (a1 > 0.f) ? a1 : expm1f(a1);
  a2 = (a2 > 0.f) ? a2 : expm1f(a2);
  a3 = (a3 > 0.f) ? a3 : expm1f(a3);
  f16x4 oh, ol;
  f16 q0 = (f16)a0; oh[0] = q0; ol[0] = (f16)(a0 - (float)q0);
  f16 q1 = (f16)a1; oh[1] = q1; ol[1] = (f16)(a1 - (float)q1);
  f16 q2 = (f16)a2; oh[2] = q2; ol[2] = (f16)(a2 - (float)q2);
  f16 q3 = (f16)a3; oh[3] = q3; ol[3] = (f16)(a3 - (float)q3);
  ((f16x4*)Oh)[self] = oh;
  ((f16x4*)Ol)[self] = ol;
}

// ---------------- pooling (sorted batch -> ranges) + final linear -------------
__global__ __launch_bounds__(256) void find_start(const int* __restrict__ batch,
                                                  int* __restrict__ gstart) {
  int g = blockIdx.x * 256 + threadIdx.x;
  if (g <= NUM_GRAPHS) {
    int lo = 0, hi = N_NODES;
    while (lo < hi) {
      int mid = (lo + hi) >> 1;
      if (batch[mid] < g) lo = mid + 1; else hi = mid;
    }
    gstart[g] = lo;
  }
}

__global__ __launch_bounds__(256) void pool_final(
    const f16* __restrict__ Hh, const f16* __restrict__ Hl,
    const int* __restrict__ gstart,
    const float* __restrict__ W, const float* __restrict__ b,
    float* __restrict__ out) {
  int g = blockIdx.x;
  __shared__ float part[NCLS * 256];
  int f = threadIdx.x;
  int s = gstart[g], e = gstart[g + 1];
  float sum = 0.f;
  for (int n = s; n < e; ++n) {
    size_t o = (size_t)n * HID + f;
    sum += (float)Hh[o] + (float)Hl[o];
  }
  float v = sum / fmaxf((float)(e - s), 1.0f);
#pragma unroll
  for (int c = 0; c < NCLS; ++c) part[c * 256 + f] = v * W[f * NCLS + c];
  __syncthreads();
  for (int off = 128; off > 0; off >>= 1) {
    if (f < off) {
#pragma unroll
      for (int c = 0; c < NCLS; ++c) part[c * 256 + f] += part[c * 256 + f + off];
    }
    __syncthreads();
  }
  if (f < NCLS) out[g * NCLS + f] = part[f * 256] + b[f];
}

extern "C" void kernel_launch(void* const* d_in, const int* in_sizes, int n_in,
                              void* d_out, int out_size, void* d_ws, size_t ws_size,
                              hipStream_t stream) {
  const float* x = (const float*)d_in[0];
  const int* ei = (const int*)d_in[1];
  const int* e_src = ei;
  const int* e_dst = ei + N_EDGES;
  const float* ea = (const float*)d_in[2];
  const int* batch = (const int*)d_in[4];
  const float* enc1_w = (const float*)d_in[5];
  const float* enc1_b = (const float*)d_in[6];
  const float* enc2_w = (const float*)d_in[7];
  const float* enc2_b = (const float*)d_in[8];
  const float* conv_ws = (const float*)d_in[9];
  const float* conv_bs = (const float*)d_in[10];
  const float* lin1_w = (const float*)d_in[11];
  const float* lin1_b = (const float*)d_in[12];
  float* out = (float*)d_out;

  char* w = (char*)d_ws;
  size_t off = 0;
  auto alloc = [&](size_t bytes) {
    size_t o = off;
    off = (off + bytes + 255) & ~(size_t)255;
    return (void*)(w + o);
  };
  const size_t PLANE = (size_t)N_NODES * HID;
  f16* Ahp = (f16*)alloc(PLANE * 2);
  f16* Alp = (f16*)alloc(PLANE * 2);
  f16* Bhp = (f16*)alloc(PLANE * 2);
  f16* Blp = (f16*)alloc(PLANE * 2);
  const size_t WTOT = 16384 + 32768 + 4 * 65536;
  f16* wth = (f16*)alloc(WTOT * 2);
  f16* wtl = (f16*)alloc(WTOT * 2);
  unsigned long long* dpack = (unsigned long long*)alloc((size_t)N_NODES * 8);
  float* dinv = (float*)alloc((size_t)N_NODES * 4);
  int* row_ptr = (int*)alloc((size_t)(N_NODES + 1) * 4);
  int* cursor = (int*)alloc((size_t)N_NODES * 4);
  int* bsum = (int*)alloc((size_t)256 * 4);
  int* csr_src = (int*)alloc((size_t)N_EDGES * 4);
  float* csr_coef = (float*)alloc((size_t)N_EDGES * 4);
  int* gstart = (int*)alloc((size_t)(NUM_GRAPHS + 1) * 4);
  (void)ws_size; (void)in_sizes; (void)n_in; (void)out_size;

  hipMemsetAsync(dpack, 0, (size_t)N_NODES * 8, stream);
  hipMemsetAsync(cursor, 0, (size_t)N_NODES * 4, stream);

  const int nb_nodes = (N_NODES + 255) / 256;
  const int nb_edges = (N_EDGES + 255) / 256;

  // graph normalization + CSR (feature-independent)
  deg_accum<<<nb_edges, 256, 0, stream>>>(e_dst, ea, dpack, N_EDGES);
  scan_p1<<<nb_nodes, 256, 0, stream>>>(dpack, dinv, bsum, N_NODES);
  scan_p2<<<1, 256, 0, stream>>>(bsum, nb_nodes, row_ptr + N_NODES);
  scan_p3<<<nb_nodes, 256, 0, stream>>>(dpack, bsum, row_ptr, N_NODES);
  csr_fill<<<nb_edges, 256, 0, stream>>>(e_src, e_dst, ea, dinv, row_ptr, cursor,
                                         csr_src, csr_coef, N_EDGES);
  find_start<<<(NUM_GRAPHS + 256) / 256, 256, 0, stream>>>(batch, gstart);

  // split x into f16 planes (aliased into B planes; dead after enc1)
  f16* xh = Bhp;
  f16* xl = Blp;
  {
    int n4 = N_NODES * F_IN / 4;
    split_f32<<<(n4 + 255) / 256, 256, 0, stream>>>(x, xh, xl, n4);
  }
  // weight transpose+split
  f16* e1h = wth;            f16* e1l = wtl;
  f16* e2h = wth + 16384;    f16* e2l = wtl + 16384;
  f16* cvh = wth + 49152;    f16* cvl = wtl + 49152;
  tsplit<<<(16384 + 255) / 256, 256, 0, stream>>>(enc1_w, e1h, e1l, F_IN, F_IN, 16384);
  tsplit<<<(32768 + 255) / 256, 256, 0, stream>>>(enc2_w, e2h, e2l, F_IN, HID, 32768);
  tsplit<<<(262144 + 255) / 256, 256, 0, stream>>>(conv_ws, cvh, cvl, HID, HID, 262144);

  const int gR = (N_NODES + 127) / 128;  // 391

  // enc1: x@W1+b1 -> A planes [50000][128]
  {
    dim3 grid(gR, 1);
    gemm_mfma<<<grid, 256, 0, stream>>>(xh, xl, e1h, e1l, enc1_b,
                                        Ahp, Alp, N_NODES, F_IN, F_IN);
  }
  // enc2: h0@W2+b2 -> B planes [50000][256] (overwrites dead x region)
  {
    dim3 grid(gR, 2);
    gemm_mfma<<<grid, 256, 0, stream>>>(Ahp, Alp, e2h, e2l, enc2_b,
                                        Bhp, Blp, N_NODES, F_IN, HID);
  }

  // 4 GCN layers: hW = h@W (B->A); aggregate+bias+ELU (A->B, hi-only neighbors)
  for (int layer = 0; layer < 4; ++layer) {
    dim3 grid(gR, 2);
    gemm_mfma<<<grid, 256, 0, stream>>>(Bhp, Blp,
                                        cvh + (size_t)layer * 65536,
                                        cvl + (size_t)layer * 65536,
                                        nullptr, Ahp, Alp, N_NODES, HID, HID);
    gather_elu<<<(N_NODES + 3) / 4, 256, 0, stream>>>(
        Ahp, Alp, dinv, row_ptr, csr_src, csr_coef,
        conv_bs + (size_t)layer * HID, Bhp, Blp);
  }

  // deterministic mean-pool per graph + final linear (fused)
  pool_final<<<NUM_GRAPHS, 256, 0, stream>>>(Bhp, Blp, gstart, lin1_w, lin1_b, out);
}

// Round 13
// 638.521 us; speedup vs baseline: 1.2900x; 1.2900x over previous
//
#include <hip/hip_runtime.h>
#include <hip/hip_bf16.h>
#include <math.h>

#define N_NODES 50000
#define N_EDGES 800000
#define NUM_GRAPHS 500
#define F_IN 128
#define HID 256
#define NCLS 10

typedef _Float16 f16;
typedef _Float16 f16x8 __attribute__((ext_vector_type(8)));
typedef _Float16 f16x4 __attribute__((ext_vector_type(4)));
typedef float f32x4 __attribute__((ext_vector_type(4)));

#define LOW40 ((1ULL << 40) - 1)

// ---------------- fp32 -> (hi,lo) f16 split, elementwise (float4/thread) ------
__global__ __launch_bounds__(256) void split_f32(const float* __restrict__ in,
                                                 f16* __restrict__ hi,
                                                 f16* __restrict__ lo, int n4) {
  int i = blockIdx.x * 256 + threadIdx.x;
  if (i < n4) {
    float4 v = ((const float4*)in)[i];
    f16x4 h, l;
    f16 h0 = (f16)v.x; h[0] = h0; l[0] = (f16)(v.x - (float)h0);
    f16 h1 = (f16)v.y; h[1] = h1; l[1] = (f16)(v.y - (float)h1);
    f16 h2 = (f16)v.z; h[2] = h2; l[2] = (f16)(v.z - (float)h2);
    f16 h3 = (f16)v.w; h[3] = h3; l[3] = (f16)(v.w - (float)h3);
    ((f16x4*)hi)[i] = h;
    ((f16x4*)lo)[i] = l;
  }
}

// -------- weight transpose + split: W[b][K][Mc] -> T[b][Mc][K] (hi,lo) --------
__global__ __launch_bounds__(256) void tsplit(const float* __restrict__ W,
                                              f16* __restrict__ Th,
                                              f16* __restrict__ Tl,
                                              int K, int Mc, int total) {
  int tid = blockIdx.x * 256 + threadIdx.x;
  if (tid < total) {
    int km = K * Mc;
    int b = tid / km;
    int rem = tid - b * km;
    int m = rem / K;
    int k = rem - m * K;
    float v = W[(size_t)b * km + (size_t)k * Mc + m];
    f16 h = (f16)v;
    Th[tid] = h;
    Tl[tid] = (f16)(v - (float)h);
  }
}

// ---- combined encoder weight: Wc[128][256] = W1[128][128] @ W2[128][256] ----
__global__ __launch_bounds__(256) void wc_gemm(const float* __restrict__ W1,
                                               const float* __restrict__ W2,
                                               float* __restrict__ Wc) {
  int tid = blockIdx.x * 256 + threadIdx.x;  // 128*256 elements
  if (tid < F_IN * HID) {
    int k = tid >> 8;   // row in W1 (0..127)
    int m = tid & 255;  // col in W2
    float s = 0.f;
    for (int j = 0; j < F_IN; ++j) s += W1[k * F_IN + j] * W2[j * HID + m];
    Wc[tid] = s;
  }
}
// bc[256] = b1 @ W2 + b2
__global__ __launch_bounds__(256) void bc_gemv(const float* __restrict__ b1,
                                               const float* __restrict__ W2,
                                               const float* __restrict__ b2,
                                               float* __restrict__ bc) {
  int m = threadIdx.x;
  float s = b2[m];
  for (int j = 0; j < F_IN; ++j) s += b1[j] * W2[j * HID + m];
  bc[m] = s;
}

// ---------------- MFMA GEMM (f16x2 emulation), LDS-staged (R11 proven) -------
#define LSTR 40

__global__ __launch_bounds__(256) void gemm_mfma(
    const f16* __restrict__ Ah, const f16* __restrict__ Al,
    const f16* __restrict__ Bth, const f16* __restrict__ Btl,
    const float* __restrict__ bias,
    f16* __restrict__ Ch, f16* __restrict__ Cl,
    int M, int K, int Nc) {
  __shared__ f16 Ash[128 * LSTR];
  __shared__ f16 Asl[128 * LSTR];
  __shared__ f16 Bsh[128 * LSTR];
  __shared__ f16 Bsl[128 * LSTR];
  const int t = threadIdx.x;
  const int lane = t & 63;
  const int wave = t >> 6;
  const int wm = wave >> 1;
  const int wn = wave & 1;
  const int row0 = blockIdx.x * 128 + wm * 64;
  const int col0 = blockIdx.y * 128 + wn * 64;
  const int brow0 = blockIdx.x * 128;
  const int bcol0 = blockIdx.y * 128;
  const int lr = lane & 15;
  const int kg = (lane >> 4) * 8;

  f32x4 acc[4][4];
  const f32x4 vzero = {0.f, 0.f, 0.f, 0.f};
#pragma unroll
  for (int m = 0; m < 4; ++m)
#pragma unroll
    for (int n = 0; n < 4; ++n) acc[m][n] = vzero;

  const int srow = t >> 2;
  const int sq8 = (t & 3) * 8;
  int arow = brow0 + srow; if (arow > M - 1) arow = M - 1;
  int arow2 = brow0 + srow + 64; if (arow2 > M - 1) arow2 = M - 1;
  const size_t gA0 = (size_t)arow * K + sq8;
  const size_t gA1 = (size_t)arow2 * K + sq8;
  const size_t gB0 = (size_t)(bcol0 + srow) * K + sq8;
  const size_t gB1 = (size_t)(bcol0 + srow + 64) * K + sq8;
  const int l0 = srow * LSTR + sq8;
  const int l1 = (srow + 64) * LSTR + sq8;

#pragma unroll 1
  for (int k0 = 0; k0 < K; k0 += 32) {
    f16x8 va0 = *(const f16x8*)(Ah + gA0 + k0);
    f16x8 va1 = *(const f16x8*)(Ah + gA1 + k0);
    f16x8 wa0 = *(const f16x8*)(Al + gA0 + k0);
    f16x8 wa1 = *(const f16x8*)(Al + gA1 + k0);
    f16x8 vb0 = *(const f16x8*)(Bth + gB0 + k0);
    f16x8 vb1 = *(const f16x8*)(Bth + gB1 + k0);
    f16x8 wb0 = *(const f16x8*)(Btl + gB0 + k0);
    f16x8 wb1 = *(const f16x8*)(Btl + gB1 + k0);
    *(f16x8*)(Ash + l0) = va0;
    *(f16x8*)(Ash + l1) = va1;
    *(f16x8*)(Asl + l0) = wa0;
    *(f16x8*)(Asl + l1) = wa1;
    *(f16x8*)(Bsh + l0) = vb0;
    *(f16x8*)(Bsh + l1) = vb1;
    *(f16x8*)(Bsl + l0) = wb0;
    *(f16x8*)(Bsl + l1) = wb1;
    __syncthreads();
    f16x8 ah[4], al[4], bh[4], bl[4];
    const int abase = wm * 64 + lr;
    const int bbase = wn * 64 + lr;
#pragma unroll
    for (int m = 0; m < 4; ++m) {
      ah[m] = *(const f16x8*)(Ash + (abase + m * 16) * LSTR + kg);
      al[m] = *(const f16x8*)(Asl + (abase + m * 16) * LSTR + kg);
    }
#pragma unroll
    for (int n = 0; n < 4; ++n) {
      bh[n] = *(const f16x8*)(Bsh + (bbase + n * 16) * LSTR + kg);
      bl[n] = *(const f16x8*)(Bsl + (bbase + n * 16) * LSTR + kg);
    }
#pragma unroll
    for (int m = 0; m < 4; ++m)
#pragma unroll
      for (int n = 0; n < 4; ++n) {
        acc[m][n] = __builtin_amdgcn_mfma_f32_16x16x32_f16(ah[m], bh[n], acc[m][n], 0, 0, 0);
        acc[m][n] = __builtin_amdgcn_mfma_f32_16x16x32_f16(ah[m], bl[n], acc[m][n], 0, 0, 0);
        acc[m][n] = __builtin_amdgcn_mfma_f32_16x16x32_f16(al[m], bh[n], acc[m][n], 0, 0, 0);
      }
    __syncthreads();
  }

  const int rbase = (lane >> 4) * 4;
#pragma unroll
  for (int m = 0; m < 4; ++m) {
#pragma unroll
    for (int r = 0; r < 4; ++r) {
      int row = row0 + m * 16 + rbase + r;
      if (row < M) {
#pragma unroll
        for (int n = 0; n < 4; ++n) {
          int col = col0 + n * 16 + lr;
          float v = acc[m][n][r];
          if (bias) v += bias[col];
          f16 h = (f16)v;
          size_t o = (size_t)row * Nc + col;
          Ch[o] = h;
          Cl[o] = (f16)(v - (float)h);
        }
      }
    }
  }
}

// ------- degree + CSR position in ONE packed u64 atomic per edge -------------
// bits [63:40] = count, bits [39:0] = sum(ew * 2^24) fixed-point.
// returned old count = this edge's slot within its dst row.
__global__ __launch_bounds__(256) void deg_pos(
    const int* __restrict__ dst, const float* __restrict__ ew,
    unsigned long long* __restrict__ dpack, int* __restrict__ tmp_pos, int E) {
  int e = blockIdx.x * 256 + threadIdx.x;
  if (e < E) {
    unsigned long long v = (1ULL << 40) |
        (unsigned long long)(unsigned)(ew[e] * 16777216.0f + 0.5f);
    unsigned long long old = atomicAdd(&dpack[dst[e]], v);
    tmp_pos[e] = (int)(old >> 40);
  }
}

// ---------------- hierarchical exclusive scan + dinv (from packed) -----------
__global__ __launch_bounds__(256) void scan_p1(
    const unsigned long long* __restrict__ dpack,
    float* __restrict__ dinv, int* __restrict__ bsum, int n) {
  __shared__ int s[256];
  int i = blockIdx.x * 256 + threadIdx.x;
  int c = 0;
  if (i < n) {
    unsigned long long v = dpack[i];
    c = (int)(v >> 40);
    float d = (float)(v & LOW40) * (1.0f / 16777216.0f);
    dinv[i] = rsqrtf(d + 1.0f);
  }
  s[threadIdx.x] = c;
  __syncthreads();
  for (int off = 128; off > 0; off >>= 1) {
    if (threadIdx.x < off) s[threadIdx.x] += s[threadIdx.x + off];
    __syncthreads();
  }
  if (threadIdx.x == 0) bsum[blockIdx.x] = s[0];
}

__global__ __launch_bounds__(256) void scan_p2(int* __restrict__ bsum, int nb,
                                               int* __restrict__ total_out) {
  __shared__ int s[256];
  int t = threadIdx.x;
  int v = (t < nb) ? bsum[t] : 0;
  s[t] = v;
  __syncthreads();
  for (int off = 1; off < 256; off <<= 1) {
    int u = (t >= off) ? s[t - off] : 0;
    __syncthreads();
    s[t] += u;
    __syncthreads();
  }
  if (t < nb) bsum[t] = s[t] - v;
  if (t == 255) *total_out = s[255];
}

__global__ __launch_bounds__(256) void scan_p3(
    const unsigned long long* __restrict__ dpack,
    const int* __restrict__ bsum, int* __restrict__ row_ptr, int n) {
  __shared__ int s[256];
  int i = blockIdx.x * 256 + threadIdx.x;
  int t = threadIdx.x;
  int v = (i < n) ? (int)(dpack[i] >> 40) : 0;
  s[t] = v;
  __syncthreads();
  for (int off = 1; off < 256; off <<= 1) {
    int u = (t >= off) ? s[t - off] : 0;
    __syncthreads();
    s[t] += u;
    __syncthreads();
  }
  if (i < n) row_ptr[i] = bsum[blockIdx.x] + s[t] - v;
}

// ---------------- CSR fill (no atomic: slot precomputed) ----------------
__global__ __launch_bounds__(256) void csr_fill(
    const int* __restrict__ src, const int* __restrict__ dst,
    const float* __restrict__ ew, const float* __restrict__ dinv,
    const int* __restrict__ row_ptr, const int* __restrict__ tmp_pos,
    int* __restrict__ csr_src, float* __restrict__ csr_coef, int E) {
  int e = blockIdx.x * 256 + threadIdx.x;
  if (e < E) {
    int s = src[e], d = dst[e];
    int idx = row_ptr[d] + tmp_pos[e];
    csr_src[idx] = s;
    csr_coef[idx] = dinv[s] * ew[e] * dinv[d];
  }
}

// -- aggregation + bias + ELU: neighbors read HI PLANE ONLY (halves traffic) --
__global__ __launch_bounds__(256) void gather_elu(
    const f16* __restrict__ Hh, const f16* __restrict__ Hl,
    const float* __restrict__ dinv, const int* __restrict__ row_ptr,
    const int* __restrict__ csr_src, const float* __restrict__ csr_coef,
    const float* __restrict__ bias,
    f16* __restrict__ Oh, f16* __restrict__ Ol) {
  const int wave = threadIdx.x >> 6;
  const int lane = threadIdx.x & 63;
  const int n = blockIdx.x * 4 + wave;
  if (n >= N_NODES) return;
  const f16x4* hh4 = (const f16x4*)Hh;
  const int start = row_ptr[n], end = row_ptr[n + 1];
  const float di = dinv[n];
  const float cself = di * di;
  size_t self = (size_t)n * 64 + lane;
  f16x4 sh = hh4[self];
  f16x4 sl = ((const f16x4*)Hl)[self];
  float a0 = cself * ((float)sh[0] + (float)sl[0]);
  float a1 = cself * ((float)sh[1] + (float)sl[1]);
  float a2 = cself * ((float)sh[2] + (float)sl[2]);
  float a3 = cself * ((float)sh[3] + (float)sl[3]);
  const int npairs = (end - start) >> 1;
  int e = start;
  if (npairs > 0) {
    int s0 = csr_src[e], s1 = csr_src[e + 1];
    float w0 = csr_coef[e], w1 = csr_coef[e + 1];
    for (int p = 1; p < npairs; ++p) {
      e += 2;
      f16x4 v0 = hh4[(size_t)s0 * 64 + lane];
      f16x4 v1 = hh4[(size_t)s1 * 64 + lane];
      int t0 = csr_src[e], t1 = csr_src[e + 1];
      float u0 = csr_coef[e], u1 = csr_coef[e + 1];
      a0 += w0 * (float)v0[0] + w1 * (float)v1[0];
      a1 += w0 * (float)v0[1] + w1 * (float)v1[1];
      a2 += w0 * (float)v0[2] + w1 * (float)v1[2];
      a3 += w0 * (float)v0[3] + w1 * (float)v1[3];
      s0 = t0; s1 = t1; w0 = u0; w1 = u1;
    }
    f16x4 v0 = hh4[(size_t)s0 * 64 + lane];
    f16x4 v1 = hh4[(size_t)s1 * 64 + lane];
    a0 += w0 * (float)v0[0] + w1 * (float)v1[0];
    a1 += w0 * (float)v0[1] + w1 * (float)v1[1];
    a2 += w0 * (float)v0[2] + w1 * (float)v1[2];
    a3 += w0 * (float)v0[3] + w1 * (float)v1[3];
    e += 2;
  }
  if (e < end) {
    int s0 = csr_src[e];
    float w0 = csr_coef[e];
    f16x4 v0 = hh4[(size_t)s0 * 64 + lane];
    a0 += w0 * (float)v0[0];
    a1 += w0 * (float)v0[1];
    a2 += w0 * (float)v0[2];
    a3 += w0 * (float)v0[3];
  }
  float4 bb = ((const float4*)bias)[lane];
  a0 += bb.x; a1 += bb.y; a2 += bb.z; a3 += bb.w;
  a0 = (a0 > 0.f) ? a0 : expm1f(a0);
  a1 = (a1 > 0.f) ? a1 : expm1f(a1);
  a2 = (a2 > 0.f) ? a2 : expm1f(a2);
  a3 = (a3 > 0.f) ? a3 : expm1f(a3);
  f16x4 oh, ol;
  f16 q0 = (f16)a0; oh[0] = q0; ol[0] = (f16)(a0 - (float)q0);
  f16 q1 = (f16)a1; oh[1] = q1; ol[1] = (f16)(a1 - (float)q1);
  f16 q2 = (f16)a2; oh[2] = q2; ol[2] = (f16)(a2 - (float)q2);
  f16 q3 = (f16)a3; oh[3] = q3; ol[3] = (f16)(a3 - (float)q3);
  ((f16x4*)Oh)[self] = oh;
  ((f16x4*)Ol)[self] = ol;
}

// ---------------- pooling (sorted batch -> ranges) + final linear -------------
__global__ __launch_bounds__(256) void find_start(const int* __restrict__ batch,
                                                  int* __restrict__ gstart) {
  int g = blockIdx.x * 256 + threadIdx.x;
  if (g <= NUM_GRAPHS) {
    int lo = 0, hi = N_NODES;
    while (lo < hi) {
      int mid = (lo + hi) >> 1;
      if (batch[mid] < g) lo = mid + 1; else hi = mid;
    }
    gstart[g] = lo;
  }
}

__global__ __launch_bounds__(256) void pool_final(
    const f16* __restrict__ Hh, const f16* __restrict__ Hl,
    const int* __restrict__ gstart,
    const float* __restrict__ W, const float* __restrict__ b,
    float* __restrict__ out) {
  int g = blockIdx.x;
  __shared__ float part[NCLS * 256];
  int f = threadIdx.x;
  int s = gstart[g], e = gstart[g + 1];
  float sum = 0.f;
  for (int n = s; n < e; ++n) {
    size_t o = (size_t)n * HID + f;
    sum += (float)Hh[o] + (float)Hl[o];
  }
  float v = sum / fmaxf((float)(e - s), 1.0f);
#pragma unroll
  for (int c = 0; c < NCLS; ++c) part[c * 256 + f] = v * W[f * NCLS + c];
  __syncthreads();
  for (int off = 128; off > 0; off >>= 1) {
    if (f < off) {
#pragma unroll
      for (int c = 0; c < NCLS; ++c) part[c * 256 + f] += part[c * 256 + f + off];
    }
    __syncthreads();
  }
  if (f < NCLS) out[g * NCLS + f] = part[f * 256] + b[f];
}

extern "C" void kernel_launch(void* const* d_in, const int* in_sizes, int n_in,
                              void* d_out, int out_size, void* d_ws, size_t ws_size,
                              hipStream_t stream) {
  const float* x = (const float*)d_in[0];
  const int* ei = (const int*)d_in[1];
  const int* e_src = ei;
  const int* e_dst = ei + N_EDGES;
  const float* ea = (const float*)d_in[2];
  const int* batch = (const int*)d_in[4];
  const float* enc1_w = (const float*)d_in[5];
  const float* enc1_b = (const float*)d_in[6];
  const float* enc2_w = (const float*)d_in[7];
  const float* enc2_b = (const float*)d_in[8];
  const float* conv_ws = (const float*)d_in[9];
  const float* conv_bs = (const float*)d_in[10];
  const float* lin1_w = (const float*)d_in[11];
  const float* lin1_b = (const float*)d_in[12];
  float* out = (float*)d_out;

  char* w = (char*)d_ws;
  size_t off = 0;
  auto alloc = [&](size_t bytes) {
    size_t o = off;
    off = (off + bytes + 255) & ~(size_t)255;
    return (void*)(w + o);
  };
  const size_t PLANE = (size_t)N_NODES * HID;
  f16* Ahp = (f16*)alloc(PLANE * 2);
  f16* Alp = (f16*)alloc(PLANE * 2);
  f16* Bhp = (f16*)alloc(PLANE * 2);
  f16* Blp = (f16*)alloc(PLANE * 2);
  // transposed-split weights: [encC 32768][conv 4*65536]
  const size_t WTOT = 32768 + 4 * 65536;
  f16* wth = (f16*)alloc(WTOT * 2);
  f16* wtl = (f16*)alloc(WTOT * 2);
  float* wc_f32 = (float*)alloc((size_t)F_IN * HID * 4);
  float* bc = (float*)alloc((size_t)HID * 4);
  unsigned long long* dpack = (unsigned long long*)alloc((size_t)N_NODES * 8);
  float* dinv = (float*)alloc((size_t)N_NODES * 4);
  int* row_ptr = (int*)alloc((size_t)(N_NODES + 1) * 4);
  int* tmp_pos = (int*)alloc((size_t)N_EDGES * 4);
  int* bsum = (int*)alloc((size_t)256 * 4);
  int* csr_src = (int*)alloc((size_t)N_EDGES * 4);
  float* csr_coef = (float*)alloc((size_t)N_EDGES * 4);
  int* gstart = (int*)alloc((size_t)(NUM_GRAPHS + 1) * 4);
  (void)ws_size; (void)in_sizes; (void)n_in; (void)out_size;

  hipMemsetAsync(dpack, 0, (size_t)N_NODES * 8, stream);

  const int nb_nodes = (N_NODES + 255) / 256;
  const int nb_edges = (N_EDGES + 255) / 256;

  // graph normalization + CSR (feature-independent); pos from packed atomic
  deg_pos<<<nb_edges, 256, 0, stream>>>(e_dst, ea, dpack, tmp_pos, N_EDGES);
  scan_p1<<<nb_nodes, 256, 0, stream>>>(dpack, dinv, bsum, N_NODES);
  scan_p2<<<1, 256, 0, stream>>>(bsum, nb_nodes, row_ptr + N_NODES);
  scan_p3<<<nb_nodes, 256, 0, stream>>>(dpack, bsum, row_ptr, N_NODES);
  csr_fill<<<nb_edges, 256, 0, stream>>>(e_src, e_dst, ea, dinv, row_ptr, tmp_pos,
                                         csr_src, csr_coef, N_EDGES);
  find_start<<<(NUM_GRAPHS + 256) / 256, 256, 0, stream>>>(batch, gstart);

  // combined encoder: Wc = W1@W2 (fp32), bc = b1@W2 + b2
  wc_gemm<<<(F_IN * HID + 255) / 256, 256, 0, stream>>>(enc1_w, enc2_w, wc_f32);
  bc_gemv<<<1, 256, 0, stream>>>(enc1_b, enc2_w, enc2_b, bc);

  // split x into f16 planes (aliased into A planes; dead after enc)
  f16* xh = Ahp;
  f16* xl = Alp;
  {
    int n4 = N_NODES * F_IN / 4;
    split_f32<<<(n4 + 255) / 256, 256, 0, stream>>>(x, xh, xl, n4);
  }
  // weight transpose+split: combined encoder (K=128, Mc=256) + convs
  f16* ech = wth;            f16* ecl = wtl;
  f16* cvh = wth + 32768;    f16* cvl = wtl + 32768;
  tsplit<<<(32768 + 255) / 256, 256, 0, stream>>>(wc_f32, ech, ecl, F_IN, HID, 32768);
  tsplit<<<(262144 + 255) / 256, 256, 0, stream>>>(conv_ws, cvh, cvl, HID, HID, 262144);

  const int gR = (N_NODES + 127) / 128;  // 391

  // fused encoder: h = x@Wc + bc -> B planes [50000][256]
  {
    dim3 grid(gR, 2);
    gemm_mfma<<<grid, 256, 0, stream>>>(xh, xl, ech, ecl, bc,
                                        Bhp, Blp, N_NODES, F_IN, HID);
  }

  // 4 GCN layers: hW = h@W (B->A); aggregate+bias+ELU (A->B, hi-only neighbors)
  for (int layer = 0; layer < 4; ++layer) {
    dim3 grid(gR, 2);
    gemm_mfma<<<grid, 256, 0, stream>>>(Bhp, Blp,
                                        cvh + (size_t)layer * 65536,
                                        cvl + (size_t)layer * 65536,
                                        nullptr, Ahp, Alp, N_NODES, HID, HID);
    gather_elu<<<(N_NODES + 3) / 4, 256, 0, stream>>>(
        Ahp, Alp, dinv, row_ptr, csr_src, csr_coef,
        conv_bs + (size_t)layer * HID, Bhp, Blp);
  }

  // deterministic mean-pool per graph + final linear (fused)
  pool_final<<<NUM_GRAPHS, 256, 0, stream>>>(Bhp, Blp, gstart, lin1_w, lin1_b, out);
}

// Round 14
// 558.768 us; speedup vs baseline: 1.4741x; 1.1427x over previous
//
#include <hip/hip_runtime.h>
#include <hip/hip_bf16.h>
#include <math.h>

#define N_NODES 50000
#define N_EDGES 800000
#define NUM_GRAPHS 500
#define F_IN 128
#define HID 256
#define NCLS 10

typedef _Float16 f16;
typedef _Float16 f16x8 __attribute__((ext_vector_type(8)));
typedef _Float16 f16x4 __attribute__((ext_vector_type(4)));
typedef float f32x4 __attribute__((ext_vector_type(4)));

#define LOW40 ((1ULL << 40) - 1)

// ---------------- fp32 -> f16 (activations: single plane) ----------------
__global__ __launch_bounds__(256) void split_hi(const float* __restrict__ in,
                                                f16* __restrict__ hi, int n4) {
  int i = blockIdx.x * 256 + threadIdx.x;
  if (i < n4) {
    float4 v = ((const float4*)in)[i];
    f16x4 h;
    h[0] = (f16)v.x; h[1] = (f16)v.y; h[2] = (f16)v.z; h[3] = (f16)v.w;
    ((f16x4*)hi)[i] = h;
  }
}

// -------- weight transpose + split: W[b][K][Mc] -> T[b][Mc][K] (hi,lo) --------
// weights keep hi+lo (coherent error across nodes does not pool away)
__global__ __launch_bounds__(256) void tsplit(const float* __restrict__ W,
                                              f16* __restrict__ Th,
                                              f16* __restrict__ Tl,
                                              int K, int Mc, int total) {
  int tid = blockIdx.x * 256 + threadIdx.x;
  if (tid < total) {
    int km = K * Mc;
    int b = tid / km;
    int rem = tid - b * km;
    int m = rem / K;
    int k = rem - m * K;
    float v = W[(size_t)b * km + (size_t)k * Mc + m];
    f16 h = (f16)v;
    Th[tid] = h;
    Tl[tid] = (f16)(v - (float)h);
  }
}

// ---- combined encoder weight: Wc[128][256] = W1[128][128] @ W2[128][256] ----
__global__ __launch_bounds__(256) void wc_gemm(const float* __restrict__ W1,
                                               const float* __restrict__ W2,
                                               float* __restrict__ Wc) {
  int tid = blockIdx.x * 256 + threadIdx.x;
  if (tid < F_IN * HID) {
    int k = tid >> 8;
    int m = tid & 255;
    float s = 0.f;
    for (int j = 0; j < F_IN; ++j) s += W1[k * F_IN + j] * W2[j * HID + m];
    Wc[tid] = s;
  }
}
// bc[256] = b1 @ W2 + b2
__global__ __launch_bounds__(256) void bc_gemv(const float* __restrict__ b1,
                                               const float* __restrict__ W2,
                                               const float* __restrict__ b2,
                                               float* __restrict__ bc) {
  int m = threadIdx.x;
  float s = b2[m];
  for (int j = 0; j < F_IN; ++j) s += b1[j] * W2[j * HID + m];
  bc[m] = s;
}

// -------- MFMA GEMM: f16 activations x (hi+lo) weights, LDS-staged ----------
// C = A @ (Bh+Bl) ~ a*bh + a*bl ; Bt transposed [Nc][K]. 4 waves (2x2),
// tile 128x128, BK=32, 32 MFMA/k-step. LDS 3 planes [128][40] f16 = 31KB.
#define LSTR 40

__global__ __launch_bounds__(256) void gemm_mfma(
    const f16* __restrict__ A,
    const f16* __restrict__ Bth, const f16* __restrict__ Btl,
    const float* __restrict__ bias,
    f16* __restrict__ C,
    int M, int K, int Nc) {
  __shared__ f16 Ash[128 * LSTR];
  __shared__ f16 Bsh[128 * LSTR];
  __shared__ f16 Bsl[128 * LSTR];
  const int t = threadIdx.x;
  const int lane = t & 63;
  const int wave = t >> 6;
  const int wm = wave >> 1;
  const int wn = wave & 1;
  const int row0 = blockIdx.x * 128 + wm * 64;
  const int col0 = blockIdx.y * 128 + wn * 64;
  const int brow0 = blockIdx.x * 128;
  const int bcol0 = blockIdx.y * 128;
  const int lr = lane & 15;
  const int kg = (lane >> 4) * 8;

  f32x4 acc[4][4];
  const f32x4 vzero = {0.f, 0.f, 0.f, 0.f};
#pragma unroll
  for (int m = 0; m < 4; ++m)
#pragma unroll
    for (int n = 0; n < 4; ++n) acc[m][n] = vzero;

  const int srow = t >> 2;
  const int sq8 = (t & 3) * 8;
  int arow = brow0 + srow; if (arow > M - 1) arow = M - 1;
  int arow2 = brow0 + srow + 64; if (arow2 > M - 1) arow2 = M - 1;
  const size_t gA0 = (size_t)arow * K + sq8;
  const size_t gA1 = (size_t)arow2 * K + sq8;
  const size_t gB0 = (size_t)(bcol0 + srow) * K + sq8;
  const size_t gB1 = (size_t)(bcol0 + srow + 64) * K + sq8;
  const int l0 = srow * LSTR + sq8;
  const int l1 = (srow + 64) * LSTR + sq8;

#pragma unroll 1
  for (int k0 = 0; k0 < K; k0 += 32) {
    f16x8 va0 = *(const f16x8*)(A + gA0 + k0);
    f16x8 va1 = *(const f16x8*)(A + gA1 + k0);
    f16x8 vb0 = *(const f16x8*)(Bth + gB0 + k0);
    f16x8 vb1 = *(const f16x8*)(Bth + gB1 + k0);
    f16x8 wb0 = *(const f16x8*)(Btl + gB0 + k0);
    f16x8 wb1 = *(const f16x8*)(Btl + gB1 + k0);
    *(f16x8*)(Ash + l0) = va0;
    *(f16x8*)(Ash + l1) = va1;
    *(f16x8*)(Bsh + l0) = vb0;
    *(f16x8*)(Bsh + l1) = vb1;
    *(f16x8*)(Bsl + l0) = wb0;
    *(f16x8*)(Bsl + l1) = wb1;
    __syncthreads();
    f16x8 ah[4], bh[4], bl[4];
    const int abase = wm * 64 + lr;
    const int bbase = wn * 64 + lr;
#pragma unroll
    for (int m = 0; m < 4; ++m)
      ah[m] = *(const f16x8*)(Ash + (abase + m * 16) * LSTR + kg);
#pragma unroll
    for (int n = 0; n < 4; ++n) {
      bh[n] = *(const f16x8*)(Bsh + (bbase + n * 16) * LSTR + kg);
      bl[n] = *(const f16x8*)(Bsl + (bbase + n * 16) * LSTR + kg);
    }
#pragma unroll
    for (int m = 0; m < 4; ++m)
#pragma unroll
      for (int n = 0; n < 4; ++n) {
        acc[m][n] = __builtin_amdgcn_mfma_f32_16x16x32_f16(ah[m], bh[n], acc[m][n], 0, 0, 0);
        acc[m][n] = __builtin_amdgcn_mfma_f32_16x16x32_f16(ah[m], bl[n], acc[m][n], 0, 0, 0);
      }
    __syncthreads();
  }

  const int rbase = (lane >> 4) * 4;
#pragma unroll
  for (int m = 0; m < 4; ++m) {
#pragma unroll
    for (int r = 0; r < 4; ++r) {
      int row = row0 + m * 16 + rbase + r;
      if (row < M) {
#pragma unroll
        for (int n = 0; n < 4; ++n) {
          int col = col0 + n * 16 + lr;
          float v = acc[m][n][r];
          if (bias) v += bias[col];
          C[(size_t)row * Nc + col] = (f16)v;
        }
      }
    }
  }
}

// ------- degree + CSR position in ONE packed u64 atomic per edge -------------
__global__ __launch_bounds__(256) void deg_pos(
    const int* __restrict__ dst, const float* __restrict__ ew,
    unsigned long long* __restrict__ dpack, int* __restrict__ tmp_pos, int E) {
  int e = blockIdx.x * 256 + threadIdx.x;
  if (e < E) {
    unsigned long long v = (1ULL << 40) |
        (unsigned long long)(unsigned)(ew[e] * 16777216.0f + 0.5f);
    unsigned long long old = atomicAdd(&dpack[dst[e]], v);
    tmp_pos[e] = (int)(old >> 40);
  }
}

// ---------------- hierarchical exclusive scan + dinv (from packed) -----------
__global__ __launch_bounds__(256) void scan_p1(
    const unsigned long long* __restrict__ dpack,
    float* __restrict__ dinv, int* __restrict__ bsum, int n) {
  __shared__ int s[256];
  int i = blockIdx.x * 256 + threadIdx.x;
  int c = 0;
  if (i < n) {
    unsigned long long v = dpack[i];
    c = (int)(v >> 40);
    float d = (float)(v & LOW40) * (1.0f / 16777216.0f);
    dinv[i] = rsqrtf(d + 1.0f);
  }
  s[threadIdx.x] = c;
  __syncthreads();
  for (int off = 128; off > 0; off >>= 1) {
    if (threadIdx.x < off) s[threadIdx.x] += s[threadIdx.x + off];
    __syncthreads();
  }
  if (threadIdx.x == 0) bsum[blockIdx.x] = s[0];
}

__global__ __launch_bounds__(256) void scan_p2(int* __restrict__ bsum, int nb,
                                               int* __restrict__ total_out) {
  __shared__ int s[256];
  int t = threadIdx.x;
  int v = (t < nb) ? bsum[t] : 0;
  s[t] = v;
  __syncthreads();
  for (int off = 1; off < 256; off <<= 1) {
    int u = (t >= off) ? s[t - off] : 0;
    __syncthreads();
    s[t] += u;
    __syncthreads();
  }
  if (t < nb) bsum[t] = s[t] - v;
  if (t == 255) *total_out = s[255];
}

__global__ __launch_bounds__(256) void scan_p3(
    const unsigned long long* __restrict__ dpack,
    const int* __restrict__ bsum, int* __restrict__ row_ptr, int n) {
  __shared__ int s[256];
  int i = blockIdx.x * 256 + threadIdx.x;
  int t = threadIdx.x;
  int v = (i < n) ? (int)(dpack[i] >> 40) : 0;
  s[t] = v;
  __syncthreads();
  for (int off = 1; off < 256; off <<= 1) {
    int u = (t >= off) ? s[t - off] : 0;
    __syncthreads();
    s[t] += u;
    __syncthreads();
  }
  if (i < n) row_ptr[i] = bsum[blockIdx.x] + s[t] - v;
}

// ---------------- CSR fill (no atomic: slot precomputed) ----------------
__global__ __launch_bounds__(256) void csr_fill(
    const int* __restrict__ src, const int* __restrict__ dst,
    const float* __restrict__ ew, const float* __restrict__ dinv,
    const int* __restrict__ row_ptr, const int* __restrict__ tmp_pos,
    int* __restrict__ csr_src, float* __restrict__ csr_coef, int E) {
  int e = blockIdx.x * 256 + threadIdx.x;
  if (e < E) {
    int s = src[e], d = dst[e];
    int idx = row_ptr[d] + tmp_pos[e];
    csr_src[idx] = s;
    csr_coef[idx] = dinv[s] * ew[e] * dinv[d];
  }
}

// ---- aggregation + bias + ELU on f16 activations (single plane) ------------
__global__ __launch_bounds__(256) void gather_elu(
    const f16* __restrict__ H,
    const float* __restrict__ dinv, const int* __restrict__ row_ptr,
    const int* __restrict__ csr_src, const float* __restrict__ csr_coef,
    const float* __restrict__ bias,
    f16* __restrict__ O) {
  const int wave = threadIdx.x >> 6;
  const int lane = threadIdx.x & 63;
  const int n = blockIdx.x * 4 + wave;
  if (n >= N_NODES) return;
  const f16x4* h4 = (const f16x4*)H;  // 64 f16x4 per row
  const int start = row_ptr[n], end = row_ptr[n + 1];
  const float di = dinv[n];
  const float cself = di * di;
  size_t self = (size_t)n * 64 + lane;
  f16x4 sh = h4[self];
  float a0 = cself * (float)sh[0];
  float a1 = cself * (float)sh[1];
  float a2 = cself * (float)sh[2];
  float a3 = cself * (float)sh[3];
  const int npairs = (end - start) >> 1;
  int e = start;
  if (npairs > 0) {
    int s0 = csr_src[e], s1 = csr_src[e + 1];
    float w0 = csr_coef[e], w1 = csr_coef[e + 1];
    for (int p = 1; p < npairs; ++p) {
      e += 2;
      f16x4 v0 = h4[(size_t)s0 * 64 + lane];
      f16x4 v1 = h4[(size_t)s1 * 64 + lane];
      int t0 = csr_src[e], t1 = csr_src[e + 1];
      float u0 = csr_coef[e], u1 = csr_coef[e + 1];
      a0 += w0 * (float)v0[0] + w1 * (float)v1[0];
      a1 += w0 * (float)v0[1] + w1 * (float)v1[1];
      a2 += w0 * (float)v0[2] + w1 * (float)v1[2];
      a3 += w0 * (float)v0[3] + w1 * (float)v1[3];
      s0 = t0; s1 = t1; w0 = u0; w1 = u1;
    }
    f16x4 v0 = h4[(size_t)s0 * 64 + lane];
    f16x4 v1 = h4[(size_t)s1 * 64 + lane];
    a0 += w0 * (float)v0[0] + w1 * (float)v1[0];
    a1 += w0 * (float)v0[1] + w1 * (float)v1[1];
    a2 += w0 * (float)v0[2] + w1 * (float)v1[2];
    a3 += w0 * (float)v0[3] + w1 * (float)v1[3];
    e += 2;
  }
  if (e < end) {
    int s0 = csr_src[e];
    float w0 = csr_coef[e];
    f16x4 v0 = h4[(size_t)s0 * 64 + lane];
    a0 += w0 * (float)v0[0];
    a1 += w0 * (float)v0[1];
    a2 += w0 * (float)v0[2];
    a3 += w0 * (float)v0[3];
  }
  float4 bb = ((const float4*)bias)[lane];
  a0 += bb.x; a1 += bb.y; a2 += bb.z; a3 += bb.w;
  a0 = (a0 > 0.f) ? a0 : expm1f(a0);
  a1 = (a1 > 0.f) ? a1 : expm1f(a1);
  a2 = (a2 > 0.f) ? a2 : expm1f(a2);
  a3 = (a3 > 0.f) ? a3 : expm1f(a3);
  f16x4 o;
  o[0] = (f16)a0; o[1] = (f16)a1; o[2] = (f16)a2; o[3] = (f16)a3;
  ((f16x4*)O)[self] = o;
}

// ---------------- pooling (sorted batch -> ranges) + final linear -------------
__global__ __launch_bounds__(256) void find_start(const int* __restrict__ batch,
                                                  int* __restrict__ gstart) {
  int g = blockIdx.x * 256 + threadIdx.x;
  if (g <= NUM_GRAPHS) {
    int lo = 0, hi = N_NODES;
    while (lo < hi) {
      int mid = (lo + hi) >> 1;
      if (batch[mid] < g) lo = mid + 1; else hi = mid;
    }
    gstart[g] = lo;
  }
}

__global__ __launch_bounds__(256) void pool_final(
    const f16* __restrict__ H, const int* __restrict__ gstart,
    const float* __restrict__ W, const float* __restrict__ b,
    float* __restrict__ out) {
  int g = blockIdx.x;
  __shared__ float part[NCLS * 256];
  int f = threadIdx.x;
  int s = gstart[g], e = gstart[g + 1];
  float sum = 0.f;
  for (int n = s; n < e; ++n) sum += (float)H[(size_t)n * HID + f];
  float v = sum / fmaxf((float)(e - s), 1.0f);
#pragma unroll
  for (int c = 0; c < NCLS; ++c) part[c * 256 + f] = v * W[f * NCLS + c];
  __syncthreads();
  for (int off = 128; off > 0; off >>= 1) {
    if (f < off) {
#pragma unroll
      for (int c = 0; c < NCLS; ++c) part[c * 256 + f] += part[c * 256 + f + off];
    }
    __syncthreads();
  }
  if (f < NCLS) out[g * NCLS + f] = part[f * 256] + b[f];
}

extern "C" void kernel_launch(void* const* d_in, const int* in_sizes, int n_in,
                              void* d_out, int out_size, void* d_ws, size_t ws_size,
                              hipStream_t stream) {
  const float* x = (const float*)d_in[0];
  const int* ei = (const int*)d_in[1];
  const int* e_src = ei;
  const int* e_dst = ei + N_EDGES;
  const float* ea = (const float*)d_in[2];
  const int* batch = (const int*)d_in[4];
  const float* enc1_w = (const float*)d_in[5];
  const float* enc1_b = (const float*)d_in[6];
  const float* enc2_w = (const float*)d_in[7];
  const float* enc2_b = (const float*)d_in[8];
  const float* conv_ws = (const float*)d_in[9];
  const float* conv_bs = (const float*)d_in[10];
  const float* lin1_w = (const float*)d_in[11];
  const float* lin1_b = (const float*)d_in[12];
  float* out = (float*)d_out;

  char* w = (char*)d_ws;
  size_t off = 0;
  auto alloc = [&](size_t bytes) {
    size_t o = off;
    off = (off + bytes + 255) & ~(size_t)255;
    return (void*)(w + o);
  };
  const size_t PLANE = (size_t)N_NODES * HID;
  f16* Ahp = (f16*)alloc(PLANE * 2);   // activations plane A (f16)
  f16* Bhp = (f16*)alloc(PLANE * 2);   // activations plane B (f16)
  const size_t WTOT = 32768 + 4 * 65536;
  f16* wth = (f16*)alloc(WTOT * 2);
  f16* wtl = (f16*)alloc(WTOT * 2);
  float* wc_f32 = (float*)alloc((size_t)F_IN * HID * 4);
  float* bc = (float*)alloc((size_t)HID * 4);
  unsigned long long* dpack = (unsigned long long*)alloc((size_t)N_NODES * 8);
  float* dinv = (float*)alloc((size_t)N_NODES * 4);
  int* row_ptr = (int*)alloc((size_t)(N_NODES + 1) * 4);
  int* tmp_pos = (int*)alloc((size_t)N_EDGES * 4);
  int* bsum = (int*)alloc((size_t)256 * 4);
  int* csr_src = (int*)alloc((size_t)N_EDGES * 4);
  float* csr_coef = (float*)alloc((size_t)N_EDGES * 4);
  int* gstart = (int*)alloc((size_t)(NUM_GRAPHS + 1) * 4);
  (void)ws_size; (void)in_sizes; (void)n_in; (void)out_size;

  hipMemsetAsync(dpack, 0, (size_t)N_NODES * 8, stream);

  const int nb_nodes = (N_NODES + 255) / 256;
  const int nb_edges = (N_EDGES + 255) / 256;

  // graph normalization + CSR (feature-independent)
  deg_pos<<<nb_edges, 256, 0, stream>>>(e_dst, ea, dpack, tmp_pos, N_EDGES);
  scan_p1<<<nb_nodes, 256, 0, stream>>>(dpack, dinv, bsum, N_NODES);
  scan_p2<<<1, 256, 0, stream>>>(bsum, nb_nodes, row_ptr + N_NODES);
  scan_p3<<<nb_nodes, 256, 0, stream>>>(dpack, bsum, row_ptr, N_NODES);
  csr_fill<<<nb_edges, 256, 0, stream>>>(e_src, e_dst, ea, dinv, row_ptr, tmp_pos,
                                         csr_src, csr_coef, N_EDGES);
  find_start<<<(NUM_GRAPHS + 256) / 256, 256, 0, stream>>>(batch, gstart);

  // combined encoder: Wc = W1@W2 (fp32), bc = b1@W2 + b2
  wc_gemm<<<(F_IN * HID + 255) / 256, 256, 0, stream>>>(enc1_w, enc2_w, wc_f32);
  bc_gemv<<<1, 256, 0, stream>>>(enc1_b, enc2_w, enc2_b, bc);

  // x -> f16 (into A plane; dead after encoder GEMM)
  f16* xh = Ahp;
  {
    int n4 = N_NODES * F_IN / 4;
    split_hi<<<(n4 + 255) / 256, 256, 0, stream>>>(x, xh, n4);
  }
  // weight transpose+split (hi+lo): combined encoder (K=128,Mc=256) + convs
  f16* ech = wth;            f16* ecl = wtl;
  f16* cvh = wth + 32768;    f16* cvl = wtl + 32768;
  tsplit<<<(32768 + 255) / 256, 256, 0, stream>>>(wc_f32, ech, ecl, F_IN, HID, 32768);
  tsplit<<<(262144 + 255) / 256, 256, 0, stream>>>(conv_ws, cvh, cvl, HID, HID, 262144);

  const int gR = (N_NODES + 127) / 128;  // 391

  // fused encoder: h = x@Wc + bc -> B plane [50000][256]
  {
    dim3 grid(gR, 2);
    gemm_mfma<<<grid, 256, 0, stream>>>(xh, ech, ecl, bc, Bhp,
                                        N_NODES, F_IN, HID);
  }

  // 4 GCN layers: hW = h@W (B->A); aggregate+bias+ELU (A->B)
  for (int layer = 0; layer < 4; ++layer) {
    dim3 grid(gR, 2);
    gemm_mfma<<<grid, 256, 0, stream>>>(Bhp,
                                        cvh + (size_t)layer * 65536,
                                        cvl + (size_t)layer * 65536,
                                        nullptr, Ahp, N_NODES, HID, HID);
    gather_elu<<<(N_NODES + 3) / 4, 256, 0, stream>>>(
        Ahp, dinv, row_ptr, csr_src, csr_coef,
        conv_bs + (size_t)layer * HID, Bhp);
  }

  // deterministic mean-pool per graph + final linear (fused)
  pool_final<<<NUM_GRAPHS, 256, 0, stream>>>(Bhp, gstart, lin1_w, lin1_b, out);
}

// Round 15
// 544.622 us; speedup vs baseline: 1.5124x; 1.0260x over previous
//
#include <hip/hip_runtime.h>
#include <hip/hip_bf16.h>
#include <math.h>

#define N_NODES 50000
#define N_EDGES 800000
#define NUM_GRAPHS 500
#define F_IN 128
#define HID 256
#define NCLS 10

typedef _Float16 f16;
typedef _Float16 f16x8 __attribute__((ext_vector_type(8)));
typedef _Float16 f16x4 __attribute__((ext_vector_type(4)));
typedef float f32x4 __attribute__((ext_vector_type(4)));

#define LOW40 ((1ULL << 40) - 1)

// ---------------- fp32 -> f16 (activations: single plane) ----------------
__global__ __launch_bounds__(256) void split_hi(const float* __restrict__ in,
                                                f16* __restrict__ hi, int n4) {
  int i = blockIdx.x * 256 + threadIdx.x;
  if (i < n4) {
    float4 v = ((const float4*)in)[i];
    f16x4 h;
    h[0] = (f16)v.x; h[1] = (f16)v.y; h[2] = (f16)v.z; h[3] = (f16)v.w;
    ((f16x4*)hi)[i] = h;
  }
}

// -------- weight transpose + split: W[b][K][Mc] -> T[b][Mc][K] (hi,lo) --------
__global__ __launch_bounds__(256) void tsplit(const float* __restrict__ W,
                                              f16* __restrict__ Th,
                                              f16* __restrict__ Tl,
                                              int K, int Mc, int total) {
  int tid = blockIdx.x * 256 + threadIdx.x;
  if (tid < total) {
    int km = K * Mc;
    int b = tid / km;
    int rem = tid - b * km;
    int m = rem / K;
    int k = rem - m * K;
    float v = W[(size_t)b * km + (size_t)k * Mc + m];
    f16 h = (f16)v;
    Th[tid] = h;
    Tl[tid] = (f16)(v - (float)h);
  }
}

// ---- combined encoder weight: Wc[128][256] = W1[128][128] @ W2[128][256] ----
__global__ __launch_bounds__(256) void wc_gemm(const float* __restrict__ W1,
                                               const float* __restrict__ W2,
                                               float* __restrict__ Wc) {
  int tid = blockIdx.x * 256 + threadIdx.x;
  if (tid < F_IN * HID) {
    int k = tid >> 8;
    int m = tid & 255;
    float s = 0.f;
    for (int j = 0; j < F_IN; ++j) s += W1[k * F_IN + j] * W2[j * HID + m];
    Wc[tid] = s;
  }
}
// bc[256] = b1 @ W2 + b2
__global__ __launch_bounds__(256) void bc_gemv(const float* __restrict__ b1,
                                               const float* __restrict__ W2,
                                               const float* __restrict__ b2,
                                               float* __restrict__ bc) {
  int m = threadIdx.x;
  float s = b2[m];
  for (int j = 0; j < F_IN; ++j) s += b1[j] * W2[j * HID + m];
  bc[m] = s;
}

// -------- MFMA GEMM: f16 activations x (hi+lo) weights, LDS-staged ----------
// C = A @ (Bh+Bl); optional epilogue: +bias[col] (encoder) or *dscale[row]
// (conv GEMMs: folds dinv into C so gather coefs reduce to plain ew).
#define LSTR 40

__global__ __launch_bounds__(256) void gemm_mfma(
    const f16* __restrict__ A,
    const f16* __restrict__ Bth, const f16* __restrict__ Btl,
    const float* __restrict__ bias, const float* __restrict__ dscale,
    f16* __restrict__ C,
    int M, int K, int Nc) {
  __shared__ f16 Ash[128 * LSTR];
  __shared__ f16 Bsh[128 * LSTR];
  __shared__ f16 Bsl[128 * LSTR];
  const int t = threadIdx.x;
  const int lane = t & 63;
  const int wave = t >> 6;
  const int wm = wave >> 1;
  const int wn = wave & 1;
  const int row0 = blockIdx.x * 128 + wm * 64;
  const int col0 = blockIdx.y * 128 + wn * 64;
  const int brow0 = blockIdx.x * 128;
  const int bcol0 = blockIdx.y * 128;
  const int lr = lane & 15;
  const int kg = (lane >> 4) * 8;

  f32x4 acc[4][4];
  const f32x4 vzero = {0.f, 0.f, 0.f, 0.f};
#pragma unroll
  for (int m = 0; m < 4; ++m)
#pragma unroll
    for (int n = 0; n < 4; ++n) acc[m][n] = vzero;

  const int srow = t >> 2;
  const int sq8 = (t & 3) * 8;
  int arow = brow0 + srow; if (arow > M - 1) arow = M - 1;
  int arow2 = brow0 + srow + 64; if (arow2 > M - 1) arow2 = M - 1;
  const size_t gA0 = (size_t)arow * K + sq8;
  const size_t gA1 = (size_t)arow2 * K + sq8;
  const size_t gB0 = (size_t)(bcol0 + srow) * K + sq8;
  const size_t gB1 = (size_t)(bcol0 + srow + 64) * K + sq8;
  const int l0 = srow * LSTR + sq8;
  const int l1 = (srow + 64) * LSTR + sq8;

#pragma unroll 1
  for (int k0 = 0; k0 < K; k0 += 32) {
    f16x8 va0 = *(const f16x8*)(A + gA0 + k0);
    f16x8 va1 = *(const f16x8*)(A + gA1 + k0);
    f16x8 vb0 = *(const f16x8*)(Bth + gB0 + k0);
    f16x8 vb1 = *(const f16x8*)(Bth + gB1 + k0);
    f16x8 wb0 = *(const f16x8*)(Btl + gB0 + k0);
    f16x8 wb1 = *(const f16x8*)(Btl + gB1 + k0);
    *(f16x8*)(Ash + l0) = va0;
    *(f16x8*)(Ash + l1) = va1;
    *(f16x8*)(Bsh + l0) = vb0;
    *(f16x8*)(Bsh + l1) = vb1;
    *(f16x8*)(Bsl + l0) = wb0;
    *(f16x8*)(Bsl + l1) = wb1;
    __syncthreads();
    f16x8 ah[4], bh[4], bl[4];
    const int abase = wm * 64 + lr;
    const int bbase = wn * 64 + lr;
#pragma unroll
    for (int m = 0; m < 4; ++m)
      ah[m] = *(const f16x8*)(Ash + (abase + m * 16) * LSTR + kg);
#pragma unroll
    for (int n = 0; n < 4; ++n) {
      bh[n] = *(const f16x8*)(Bsh + (bbase + n * 16) * LSTR + kg);
      bl[n] = *(const f16x8*)(Bsl + (bbase + n * 16) * LSTR + kg);
    }
#pragma unroll
    for (int m = 0; m < 4; ++m)
#pragma unroll
      for (int n = 0; n < 4; ++n) {
        acc[m][n] = __builtin_amdgcn_mfma_f32_16x16x32_f16(ah[m], bh[n], acc[m][n], 0, 0, 0);
        acc[m][n] = __builtin_amdgcn_mfma_f32_16x16x32_f16(ah[m], bl[n], acc[m][n], 0, 0, 0);
      }
    __syncthreads();
  }

  const int rbase = (lane >> 4) * 4;
#pragma unroll
  for (int m = 0; m < 4; ++m) {
#pragma unroll
    for (int r = 0; r < 4; ++r) {
      int row = row0 + m * 16 + rbase + r;
      if (row < M) {
        float ds = dscale ? dscale[row] : 1.0f;
#pragma unroll
        for (int n = 0; n < 4; ++n) {
          int col = col0 + n * 16 + lr;
          float v = acc[m][n][r];
          if (bias) v += bias[col];
          v *= ds;
          C[(size_t)row * Nc + col] = (f16)v;
        }
      }
    }
  }
}

// ------- degree + CSR position in ONE packed u64 atomic per edge -------------
__global__ __launch_bounds__(256) void deg_pos(
    const int* __restrict__ dst, const float* __restrict__ ew,
    unsigned long long* __restrict__ dpack, int* __restrict__ tmp_pos, int E) {
  int e = blockIdx.x * 256 + threadIdx.x;
  if (e < E) {
    unsigned long long v = (1ULL << 40) |
        (unsigned long long)(unsigned)(ew[e] * 16777216.0f + 0.5f);
    unsigned long long old = atomicAdd(&dpack[dst[e]], v);
    tmp_pos[e] = (int)(old >> 40);
  }
}

// ---------------- hierarchical exclusive scan + dinv (from packed) -----------
__global__ __launch_bounds__(256) void scan_p1(
    const unsigned long long* __restrict__ dpack,
    float* __restrict__ dinv, int* __restrict__ bsum, int n) {
  __shared__ int s[256];
  int i = blockIdx.x * 256 + threadIdx.x;
  int c = 0;
  if (i < n) {
    unsigned long long v = dpack[i];
    c = (int)(v >> 40);
    float d = (float)(v & LOW40) * (1.0f / 16777216.0f);
    dinv[i] = rsqrtf(d + 1.0f);
  }
  s[threadIdx.x] = c;
  __syncthreads();
  for (int off = 128; off > 0; off >>= 1) {
    if (threadIdx.x < off) s[threadIdx.x] += s[threadIdx.x + off];
    __syncthreads();
  }
  if (threadIdx.x == 0) bsum[blockIdx.x] = s[0];
}

__global__ __launch_bounds__(256) void scan_p2(int* __restrict__ bsum, int nb,
                                               int* __restrict__ total_out) {
  __shared__ int s[256];
  int t = threadIdx.x;
  int v = (t < nb) ? bsum[t] : 0;
  s[t] = v;
  __syncthreads();
  for (int off = 1; off < 256; off <<= 1) {
    int u = (t >= off) ? s[t - off] : 0;
    __syncthreads();
    s[t] += u;
    __syncthreads();
  }
  if (t < nb) bsum[t] = s[t] - v;
  if (t == 255) *total_out = s[255];
}

__global__ __launch_bounds__(256) void scan_p3(
    const unsigned long long* __restrict__ dpack,
    const int* __restrict__ bsum, int* __restrict__ row_ptr, int n) {
  __shared__ int s[256];
  int i = blockIdx.x * 256 + threadIdx.x;
  int t = threadIdx.x;
  int v = (i < n) ? (int)(dpack[i] >> 40) : 0;
  s[t] = v;
  __syncthreads();
  for (int off = 1; off < 256; off <<= 1) {
    int u = (t >= off) ? s[t - off] : 0;
    __syncthreads();
    s[t] += u;
    __syncthreads();
  }
  if (i < n) row_ptr[i] = bsum[blockIdx.x] + s[t] - v;
}

// ----- CSR fill (no atomic, no dinv gather: coef = plain edge weight) --------
__global__ __launch_bounds__(256) void csr_fill(
    const int* __restrict__ src, const int* __restrict__ dst,
    const float* __restrict__ ew,
    const int* __restrict__ row_ptr, const int* __restrict__ tmp_pos,
    int* __restrict__ csr_src, float* __restrict__ csr_coef, int E) {
  int e = blockIdx.x * 256 + threadIdx.x;
  if (e < E) {
    int d = dst[e];
    int idx = row_ptr[d] + tmp_pos[e];
    csr_src[idx] = src[e];
    csr_coef[idx] = ew[e];
  }
}

// ---- aggregation + bias + ELU; C rows pre-scaled by dinv[row] --------------
// out[d] = ELU( dinv[d]*(C[d] + sum_j ew_j*C[s_j]) + bias )
// Two rows per load instruction: lanes 0-31 carry even edge, 32-63 odd edge
// (16 B/lane, 1 KB/instruction); final shfl_xor(32) combines halves.
__global__ __launch_bounds__(256) void gather_elu(
    const f16* __restrict__ C,
    const float* __restrict__ dinv, const int* __restrict__ row_ptr,
    const int* __restrict__ csr_src, const float* __restrict__ csr_coef,
    const float* __restrict__ bias,
    f16* __restrict__ O) {
  const int wave = threadIdx.x >> 6;
  const int lane = threadIdx.x & 63;
  const int n = blockIdx.x * 4 + wave;
  if (n >= N_NODES) return;
  const int li = lane & 31;       // feature-slice index: features li*8..+8
  const int sel = lane >> 5;      // 0: even edge, 1: odd edge
  const int start = row_ptr[n], end = row_ptr[n + 1];
  float a0 = 0.f, a1 = 0.f, a2 = 0.f, a3 = 0.f,
        a4 = 0.f, a5 = 0.f, a6 = 0.f, a7 = 0.f;
  int e = start;
  // 4 edges per iteration: two 1KB row-load instructions in flight
  for (; e + 4 <= end; e += 4) {
    int sa = csr_src[e + sel];
    int sb = csr_src[e + 2 + sel];
    float wa = csr_coef[e + sel];
    float wb = csr_coef[e + 2 + sel];
    f16x8 va = *(const f16x8*)(C + (size_t)sa * 256 + li * 8);
    f16x8 vb = *(const f16x8*)(C + (size_t)sb * 256 + li * 8);
    a0 += wa * (float)va[0] + wb * (float)vb[0];
    a1 += wa * (float)va[1] + wb * (float)vb[1];
    a2 += wa * (float)va[2] + wb * (float)vb[2];
    a3 += wa * (float)va[3] + wb * (float)vb[3];
    a4 += wa * (float)va[4] + wb * (float)vb[4];
    a5 += wa * (float)va[5] + wb * (float)vb[5];
    a6 += wa * (float)va[6] + wb * (float)vb[6];
    a7 += wa * (float)va[7] + wb * (float)vb[7];
  }
  if (e + 2 <= end) {  // one more pair
    int sa = csr_src[e + sel];
    float wa = csr_coef[e + sel];
    f16x8 va = *(const f16x8*)(C + (size_t)sa * 256 + li * 8);
    a0 += wa * (float)va[0]; a1 += wa * (float)va[1];
    a2 += wa * (float)va[2]; a3 += wa * (float)va[3];
    a4 += wa * (float)va[4]; a5 += wa * (float)va[5];
    a6 += wa * (float)va[6]; a7 += wa * (float)va[7];
    e += 2;
  }
  if (e < end) {  // odd tail: lower half only (upper half weight 0)
    int sa = csr_src[e];
    float wa = (sel == 0) ? csr_coef[e] : 0.f;
    f16x8 va = *(const f16x8*)(C + (size_t)sa * 256 + li * 8);
    a0 += wa * (float)va[0]; a1 += wa * (float)va[1];
    a2 += wa * (float)va[2]; a3 += wa * (float)va[3];
    a4 += wa * (float)va[4]; a5 += wa * (float)va[5];
    a6 += wa * (float)va[6]; a7 += wa * (float)va[7];
  }
  // combine even/odd halves
  a0 += __shfl_xor(a0, 32); a1 += __shfl_xor(a1, 32);
  a2 += __shfl_xor(a2, 32); a3 += __shfl_xor(a3, 32);
  a4 += __shfl_xor(a4, 32); a5 += __shfl_xor(a5, 32);
  a6 += __shfl_xor(a6, 32); a7 += __shfl_xor(a7, 32);
  // self + scale + bias + ELU (all lanes compute; lanes 0-31 write 16B each)
  const float dd = dinv[n];
  f16x8 sv = *(const f16x8*)(C + (size_t)n * 256 + li * 8);
  float4 b0 = ((const float4*)bias)[li * 2];
  float4 b1 = ((const float4*)bias)[li * 2 + 1];
  float r0 = dd * (a0 + (float)sv[0]) + b0.x;
  float r1 = dd * (a1 + (float)sv[1]) + b0.y;
  float r2 = dd * (a2 + (float)sv[2]) + b0.z;
  float r3 = dd * (a3 + (float)sv[3]) + b0.w;
  float r4 = dd * (a4 + (float)sv[4]) + b1.x;
  float r5 = dd * (a5 + (float)sv[5]) + b1.y;
  float r6 = dd * (a6 + (float)sv[6]) + b1.z;
  float r7 = dd * (a7 + (float)sv[7]) + b1.w;
  r0 = (r0 > 0.f) ? r0 : expm1f(r0);
  r1 = (r1 > 0.f) ? r1 : expm1f(r1);
  r2 = (r2 > 0.f) ? r2 : expm1f(r2);
  r3 = (r3 > 0.f) ? r3 : expm1f(r3);
  r4 = (r4 > 0.f) ? r4 : expm1f(r4);
  r5 = (r5 > 0.f) ? r5 : expm1f(r5);
  r6 = (r6 > 0.f) ? r6 : expm1f(r6);
  r7 = (r7 > 0.f) ? r7 : expm1f(r7);
  if (sel == 0) {
    f16x8 o;
    o[0] = (f16)r0; o[1] = (f16)r1; o[2] = (f16)r2; o[3] = (f16)r3;
    o[4] = (f16)r4; o[5] = (f16)r5; o[6] = (f16)r6; o[7] = (f16)r7;
    *(f16x8*)(O + (size_t)n * 256 + li * 8) = o;
  }
}

// ---------------- pooling (sorted batch -> ranges) + final linear -------------
__global__ __launch_bounds__(256) void find_start(const int* __restrict__ batch,
                                                  int* __restrict__ gstart) {
  int g = blockIdx.x * 256 + threadIdx.x;
  if (g <= NUM_GRAPHS) {
    int lo = 0, hi = N_NODES;
    while (lo < hi) {
      int mid = (lo + hi) >> 1;
      if (batch[mid] < g) lo = mid + 1; else hi = mid;
    }
    gstart[g] = lo;
  }
}

__global__ __launch_bounds__(256) void pool_final(
    const f16* __restrict__ H, const int* __restrict__ gstart,
    const float* __restrict__ W, const float* __restrict__ b,
    float* __restrict__ out) {
  int g = blockIdx.x;
  __shared__ float part[NCLS * 256];
  int f = threadIdx.x;
  int s = gstart[g], e = gstart[g + 1];
  float sum = 0.f;
  for (int n = s; n < e; ++n) sum += (float)H[(size_t)n * HID + f];
  float v = sum / fmaxf((float)(e - s), 1.0f);
#pragma unroll
  for (int c = 0; c < NCLS; ++c) part[c * 256 + f] = v * W[f * NCLS + c];
  __syncthreads();
  for (int off = 128; off > 0; off >>= 1) {
    if (f < off) {
#pragma unroll
      for (int c = 0; c < NCLS; ++c) part[c * 256 + f] += part[c * 256 + f + off];
    }
    __syncthreads();
  }
  if (f < NCLS) out[g * NCLS + f] = part[f * 256] + b[f];
}

extern "C" void kernel_launch(void* const* d_in, const int* in_sizes, int n_in,
                              void* d_out, int out_size, void* d_ws, size_t ws_size,
                              hipStream_t stream) {
  const float* x = (const float*)d_in[0];
  const int* ei = (const int*)d_in[1];
  const int* e_src = ei;
  const int* e_dst = ei + N_EDGES;
  const float* ea = (const float*)d_in[2];
  const int* batch = (const int*)d_in[4];
  const float* enc1_w = (const float*)d_in[5];
  const float* enc1_b = (const float*)d_in[6];
  const float* enc2_w = (const float*)d_in[7];
  const float* enc2_b = (const float*)d_in[8];
  const float* conv_ws = (const float*)d_in[9];
  const float* conv_bs = (const float*)d_in[10];
  const float* lin1_w = (const float*)d_in[11];
  const float* lin1_b = (const float*)d_in[12];
  float* out = (float*)d_out;

  char* w = (char*)d_ws;
  size_t off = 0;
  auto alloc = [&](size_t bytes) {
    size_t o = off;
    off = (off + bytes + 255) & ~(size_t)255;
    return (void*)(w + o);
  };
  const size_t PLANE = (size_t)N_NODES * HID;
  f16* Ahp = (f16*)alloc(PLANE * 2);   // conv GEMM out (dinv-scaled hW)
  f16* Bhp = (f16*)alloc(PLANE * 2);   // activations h
  const size_t WTOT = 32768 + 4 * 65536;
  f16* wth = (f16*)alloc(WTOT * 2);
  f16* wtl = (f16*)alloc(WTOT * 2);
  float* wc_f32 = (float*)alloc((size_t)F_IN * HID * 4);
  float* bc = (float*)alloc((size_t)HID * 4);
  unsigned long long* dpack = (unsigned long long*)alloc((size_t)N_NODES * 8);
  float* dinv = (float*)alloc((size_t)N_NODES * 4);
  int* row_ptr = (int*)alloc((size_t)(N_NODES + 1) * 4);
  int* tmp_pos = (int*)alloc((size_t)N_EDGES * 4);
  int* bsum = (int*)alloc((size_t)256 * 4);
  int* csr_src = (int*)alloc((size_t)N_EDGES * 4);
  float* csr_coef = (float*)alloc((size_t)N_EDGES * 4);
  int* gstart = (int*)alloc((size_t)(NUM_GRAPHS + 1) * 4);
  (void)ws_size; (void)in_sizes; (void)n_in; (void)out_size;

  hipMemsetAsync(dpack, 0, (size_t)N_NODES * 8, stream);

  const int nb_nodes = (N_NODES + 255) / 256;
  const int nb_edges = (N_EDGES + 255) / 256;

  // graph normalization + CSR (feature-independent)
  deg_pos<<<nb_edges, 256, 0, stream>>>(e_dst, ea, dpack, tmp_pos, N_EDGES);
  scan_p1<<<nb_nodes, 256, 0, stream>>>(dpack, dinv, bsum, N_NODES);
  scan_p2<<<1, 256, 0, stream>>>(bsum, nb_nodes, row_ptr + N_NODES);
  scan_p3<<<nb_nodes, 256, 0, stream>>>(dpack, bsum, row_ptr, N_NODES);
  csr_fill<<<nb_edges, 256, 0, stream>>>(e_src, e_dst, ea, row_ptr, tmp_pos,
                                         csr_src, csr_coef, N_EDGES);
  find_start<<<(NUM_GRAPHS + 256) / 256, 256, 0, stream>>>(batch, gstart);

  // combined encoder: Wc = W1@W2 (fp32), bc = b1@W2 + b2
  wc_gemm<<<(F_IN * HID + 255) / 256, 256, 0, stream>>>(enc1_w, enc2_w, wc_f32);
  bc_gemv<<<1, 256, 0, stream>>>(enc1_b, enc2_w, enc2_b, bc);

  // x -> f16 (into A plane; dead after encoder GEMM)
  f16* xh = Ahp;
  {
    int n4 = N_NODES * F_IN / 4;
    split_hi<<<(n4 + 255) / 256, 256, 0, stream>>>(x, xh, n4);
  }
  // weight transpose+split (hi+lo): combined encoder (K=128,Mc=256) + convs
  f16* ech = wth;            f16* ecl = wtl;
  f16* cvh = wth + 32768;    f16* cvl = wtl + 32768;
  tsplit<<<(32768 + 255) / 256, 256, 0, stream>>>(wc_f32, ech, ecl, F_IN, HID, 32768);
  tsplit<<<(262144 + 255) / 256, 256, 0, stream>>>(conv_ws, cvh, cvl, HID, HID, 262144);

  const int gR = (N_NODES + 127) / 128;  // 391

  // fused encoder: h = x@Wc + bc -> B plane
  {
    dim3 grid(gR, 2);
    gemm_mfma<<<grid, 256, 0, stream>>>(xh, ech, ecl, bc, nullptr, Bhp,
                                        N_NODES, F_IN, HID);
  }

  // 4 GCN layers: C = dinv*(h@W) (B->A); aggregate+bias+ELU (A->B)
  for (int layer = 0; layer < 4; ++layer) {
    dim3 grid(gR, 2);
    gemm_mfma<<<grid, 256, 0, stream>>>(Bhp,
                                        cvh + (size_t)layer * 65536,
                                        cvl + (size_t)layer * 65536,
                                        nullptr, dinv, Ahp, N_NODES, HID, HID);
    gather_elu<<<(N_NODES + 3) / 4, 256, 0, stream>>>(
        Ahp, dinv, row_ptr, csr_src, csr_coef,
        conv_bs + (size_t)layer * HID, Bhp);
  }

  // deterministic mean-pool per graph + final linear (fused)
  pool_final<<<NUM_GRAPHS, 256, 0, stream>>>(Bhp, gstart, lin1_w, lin1_b, out);
}

// Round 16
// 540.439 us; speedup vs baseline: 1.5241x; 1.0077x over previous
//
#include <hip/hip_runtime.h>
#include <hip/hip_bf16.h>
#include <math.h>

#define N_NODES 50000
#define N_EDGES 800000
#define NUM_GRAPHS 500
#define F_IN 128
#define HID 256
#define NCLS 10

typedef _Float16 f16;
typedef _Float16 f16x8 __attribute__((ext_vector_type(8)));
typedef _Float16 f16x4 __attribute__((ext_vector_type(4)));
typedef float f32x4 __attribute__((ext_vector_type(4)));

#define LOW40 ((1ULL << 40) - 1)

// ---------------- fp32 -> f16 (activations: single plane) ----------------
__global__ __launch_bounds__(256) void split_hi(const float* __restrict__ in,
                                                f16* __restrict__ hi, int n4) {
  int i = blockIdx.x * 256 + threadIdx.x;
  if (i < n4) {
    float4 v = ((const float4*)in)[i];
    f16x4 h;
    h[0] = (f16)v.x; h[1] = (f16)v.y; h[2] = (f16)v.z; h[3] = (f16)v.w;
    ((f16x4*)hi)[i] = h;
  }
}

// -------- weight transpose + split: W[b][K][Mc] -> T[b][Mc][K] (hi,lo) --------
__global__ __launch_bounds__(256) void tsplit(const float* __restrict__ W,
                                              f16* __restrict__ Th,
                                              f16* __restrict__ Tl,
                                              int K, int Mc, int total) {
  int tid = blockIdx.x * 256 + threadIdx.x;
  if (tid < total) {
    int km = K * Mc;
    int b = tid / km;
    int rem = tid - b * km;
    int m = rem / K;
    int k = rem - m * K;
    float v = W[(size_t)b * km + (size_t)k * Mc + m];
    f16 h = (f16)v;
    Th[tid] = h;
    Tl[tid] = (f16)(v - (float)h);
  }
}

// ---- combined encoder weight: Wc[128][256] = W1[128][128] @ W2[128][256] ----
__global__ __launch_bounds__(256) void wc_gemm(const float* __restrict__ W1,
                                               const float* __restrict__ W2,
                                               float* __restrict__ Wc) {
  int tid = blockIdx.x * 256 + threadIdx.x;
  if (tid < F_IN * HID) {
    int k = tid >> 8;
    int m = tid & 255;
    float s = 0.f;
    for (int j = 0; j < F_IN; ++j) s += W1[k * F_IN + j] * W2[j * HID + m];
    Wc[tid] = s;
  }
}
// bc[256] = b1 @ W2 + b2
__global__ __launch_bounds__(256) void bc_gemv(const float* __restrict__ b1,
                                               const float* __restrict__ W2,
                                               const float* __restrict__ b2,
                                               float* __restrict__ bc) {
  int m = threadIdx.x;
  float s = b2[m];
  for (int j = 0; j < F_IN; ++j) s += b1[j] * W2[j * HID + m];
  bc[m] = s;
}

// -------- MFMA GEMM: f16 activations x (hi+lo) weights, LDS-staged ----------
#define LSTR 40

__global__ __launch_bounds__(256) void gemm_mfma(
    const f16* __restrict__ A,
    const f16* __restrict__ Bth, const f16* __restrict__ Btl,
    const float* __restrict__ bias, const float* __restrict__ dscale,
    f16* __restrict__ C,
    int M, int K, int Nc) {
  __shared__ f16 Ash[128 * LSTR];
  __shared__ f16 Bsh[128 * LSTR];
  __shared__ f16 Bsl[128 * LSTR];
  const int t = threadIdx.x;
  const int lane = t & 63;
  const int wave = t >> 6;
  const int wm = wave >> 1;
  const int wn = wave & 1;
  const int row0 = blockIdx.x * 128 + wm * 64;
  const int col0 = blockIdx.y * 128 + wn * 64;
  const int brow0 = blockIdx.x * 128;
  const int bcol0 = blockIdx.y * 128;
  const int lr = lane & 15;
  const int kg = (lane >> 4) * 8;

  f32x4 acc[4][4];
  const f32x4 vzero = {0.f, 0.f, 0.f, 0.f};
#pragma unroll
  for (int m = 0; m < 4; ++m)
#pragma unroll
    for (int n = 0; n < 4; ++n) acc[m][n] = vzero;

  const int srow = t >> 2;
  const int sq8 = (t & 3) * 8;
  int arow = brow0 + srow; if (arow > M - 1) arow = M - 1;
  int arow2 = brow0 + srow + 64; if (arow2 > M - 1) arow2 = M - 1;
  const size_t gA0 = (size_t)arow * K + sq8;
  const size_t gA1 = (size_t)arow2 * K + sq8;
  const size_t gB0 = (size_t)(bcol0 + srow) * K + sq8;
  const size_t gB1 = (size_t)(bcol0 + srow + 64) * K + sq8;
  const int l0 = srow * LSTR + sq8;
  const int l1 = (srow + 64) * LSTR + sq8;

#pragma unroll 1
  for (int k0 = 0; k0 < K; k0 += 32) {
    f16x8 va0 = *(const f16x8*)(A + gA0 + k0);
    f16x8 va1 = *(const f16x8*)(A + gA1 + k0);
    f16x8 vb0 = *(const f16x8*)(Bth + gB0 + k0);
    f16x8 vb1 = *(const f16x8*)(Bth + gB1 + k0);
    f16x8 wb0 = *(const f16x8*)(Btl + gB0 + k0);
    f16x8 wb1 = *(const f16x8*)(Btl + gB1 + k0);
    *(f16x8*)(Ash + l0) = va0;
    *(f16x8*)(Ash + l1) = va1;
    *(f16x8*)(Bsh + l0) = vb0;
    *(f16x8*)(Bsh + l1) = vb1;
    *(f16x8*)(Bsl + l0) = wb0;
    *(f16x8*)(Bsl + l1) = wb1;
    __syncthreads();
    f16x8 ah[4], bh[4], bl[4];
    const int abase = wm * 64 + lr;
    const int bbase = wn * 64 + lr;
#pragma unroll
    for (int m = 0; m < 4; ++m)
      ah[m] = *(const f16x8*)(Ash + (abase + m * 16) * LSTR + kg);
#pragma unroll
    for (int n = 0; n < 4; ++n) {
      bh[n] = *(const f16x8*)(Bsh + (bbase + n * 16) * LSTR + kg);
      bl[n] = *(const f16x8*)(Bsl + (bbase + n * 16) * LSTR + kg);
    }
#pragma unroll
    for (int m = 0; m < 4; ++m)
#pragma unroll
      for (int n = 0; n < 4; ++n) {
        acc[m][n] = __builtin_amdgcn_mfma_f32_16x16x32_f16(ah[m], bh[n], acc[m][n], 0, 0, 0);
        acc[m][n] = __builtin_amdgcn_mfma_f32_16x16x32_f16(ah[m], bl[n], acc[m][n], 0, 0, 0);
      }
    __syncthreads();
  }

  const int rbase = (lane >> 4) * 4;
#pragma unroll
  for (int m = 0; m < 4; ++m) {
#pragma unroll
    for (int r = 0; r < 4; ++r) {
      int row = row0 + m * 16 + rbase + r;
      if (row < M) {
        float ds = dscale ? dscale[row] : 1.0f;
#pragma unroll
        for (int n = 0; n < 4; ++n) {
          int col = col0 + n * 16 + lr;
          float v = acc[m][n][r];
          if (bias) v += bias[col];
          v *= ds;
          C[(size_t)row * Nc + col] = (f16)v;
        }
      }
    }
  }
}

// ------- degree + CSR position in ONE packed u64 atomic per edge -------------
__global__ __launch_bounds__(256) void deg_pos(
    const int* __restrict__ dst, const float* __restrict__ ew,
    unsigned long long* __restrict__ dpack, int* __restrict__ tmp_pos, int E) {
  int e = blockIdx.x * 256 + threadIdx.x;
  if (e < E) {
    unsigned long long v = (1ULL << 40) |
        (unsigned long long)(unsigned)(ew[e] * 16777216.0f + 0.5f);
    unsigned long long old = atomicAdd(&dpack[dst[e]], v);
    tmp_pos[e] = (int)(old >> 40);
  }
}

// ---------------- hierarchical exclusive scan + dinv (from packed) -----------
__global__ __launch_bounds__(256) void scan_p1(
    const unsigned long long* __restrict__ dpack,
    float* __restrict__ dinv, int* __restrict__ bsum, int n) {
  __shared__ int s[256];
  int i = blockIdx.x * 256 + threadIdx.x;
  int c = 0;
  if (i < n) {
    unsigned long long v = dpack[i];
    c = (int)(v >> 40);
    float d = (float)(v & LOW40) * (1.0f / 16777216.0f);
    dinv[i] = rsqrtf(d + 1.0f);
  }
  s[threadIdx.x] = c;
  __syncthreads();
  for (int off = 128; off > 0; off >>= 1) {
    if (threadIdx.x < off) s[threadIdx.x] += s[threadIdx.x + off];
    __syncthreads();
  }
  if (threadIdx.x == 0) bsum[blockIdx.x] = s[0];
}

__global__ __launch_bounds__(256) void scan_p2(int* __restrict__ bsum, int nb,
                                               int* __restrict__ total_out) {
  __shared__ int s[256];
  int t = threadIdx.x;
  int v = (t < nb) ? bsum[t] : 0;
  s[t] = v;
  __syncthreads();
  for (int off = 1; off < 256; off <<= 1) {
    int u = (t >= off) ? s[t - off] : 0;
    __syncthreads();
    s[t] += u;
    __syncthreads();
  }
  if (t < nb) bsum[t] = s[t] - v;
  if (t == 255) *total_out = s[255];
}

__global__ __launch_bounds__(256) void scan_p3(
    const unsigned long long* __restrict__ dpack,
    const int* __restrict__ bsum, int* __restrict__ row_ptr, int n) {
  __shared__ int s[256];
  int i = blockIdx.x * 256 + threadIdx.x;
  int t = threadIdx.x;
  int v = (i < n) ? (int)(dpack[i] >> 40) : 0;
  s[t] = v;
  __syncthreads();
  for (int off = 1; off < 256; off <<= 1) {
    int u = (t >= off) ? s[t - off] : 0;
    __syncthreads();
    s[t] += u;
    __syncthreads();
  }
  if (i < n) row_ptr[i] = bsum[blockIdx.x] + s[t] - v;
}

// ----- CSR fill (no atomic, no dinv gather: coef = plain edge weight) --------
__global__ __launch_bounds__(256) void csr_fill(
    const int* __restrict__ src, const int* __restrict__ dst,
    const float* __restrict__ ew,
    const int* __restrict__ row_ptr, const int* __restrict__ tmp_pos,
    int* __restrict__ csr_src, float* __restrict__ csr_coef, int E) {
  int e = blockIdx.x * 256 + threadIdx.x;
  if (e < E) {
    int d = dst[e];
    int idx = row_ptr[d] + tmp_pos[e];
    csr_src[idx] = src[e];
    csr_coef[idx] = ew[e];
  }
}

// ---- aggregation + bias + ELU; C rows pre-scaled by dinv[row] --------------
// out[d] = ELU( dinv[d]*(C[d] + sum_j ew_j*C[s_j]) + bias )
// Lanes 0-31 carry even edges, 32-63 odd edges (16 B/lane); 8-edge unroll
// keeps 4 independent 1KB row-load instructions in flight.
__global__ __launch_bounds__(256) void gather_elu(
    const f16* __restrict__ C,
    const float* __restrict__ dinv, const int* __restrict__ row_ptr,
    const int* __restrict__ csr_src, const float* __restrict__ csr_coef,
    const float* __restrict__ bias,
    f16* __restrict__ O) {
  const int wave = threadIdx.x >> 6;
  const int lane = threadIdx.x & 63;
  const int n = blockIdx.x * 4 + wave;
  if (n >= N_NODES) return;
  const int li = lane & 31;       // feature-slice index: features li*8..+8
  const int sel = lane >> 5;      // 0: even edge, 1: odd edge
  const int start = row_ptr[n], end = row_ptr[n + 1];
  float a0 = 0.f, a1 = 0.f, a2 = 0.f, a3 = 0.f,
        a4 = 0.f, a5 = 0.f, a6 = 0.f, a7 = 0.f;
  int e = start;
  // 8 edges per iteration: four 1KB row-load instructions in flight
  for (; e + 8 <= end; e += 8) {
    int sa = csr_src[e + sel];
    int sb = csr_src[e + 2 + sel];
    int sc = csr_src[e + 4 + sel];
    int sd = csr_src[e + 6 + sel];
    float wa = csr_coef[e + sel];
    float wb = csr_coef[e + 2 + sel];
    float wc = csr_coef[e + 4 + sel];
    float wd = csr_coef[e + 6 + sel];
    f16x8 va = *(const f16x8*)(C + (size_t)sa * 256 + li * 8);
    f16x8 vb = *(const f16x8*)(C + (size_t)sb * 256 + li * 8);
    f16x8 vc = *(const f16x8*)(C + (size_t)sc * 256 + li * 8);
    f16x8 vd = *(const f16x8*)(C + (size_t)sd * 256 + li * 8);
    a0 += wa * (float)va[0] + wb * (float)vb[0] + wc * (float)vc[0] + wd * (float)vd[0];
    a1 += wa * (float)va[1] + wb * (float)vb[1] + wc * (float)vc[1] + wd * (float)vd[1];
    a2 += wa * (float)va[2] + wb * (float)vb[2] + wc * (float)vc[2] + wd * (float)vd[2];
    a3 += wa * (float)va[3] + wb * (float)vb[3] + wc * (float)vc[3] + wd * (float)vd[3];
    a4 += wa * (float)va[4] + wb * (float)vb[4] + wc * (float)vc[4] + wd * (float)vd[4];
    a5 += wa * (float)va[5] + wb * (float)vb[5] + wc * (float)vc[5] + wd * (float)vd[5];
    a6 += wa * (float)va[6] + wb * (float)vb[6] + wc * (float)vc[6] + wd * (float)vd[6];
    a7 += wa * (float)va[7] + wb * (float)vb[7] + wc * (float)vc[7] + wd * (float)vd[7];
  }
  if (e + 4 <= end) {
    int sa = csr_src[e + sel];
    int sb = csr_src[e + 2 + sel];
    float wa = csr_coef[e + sel];
    float wb = csr_coef[e + 2 + sel];
    f16x8 va = *(const f16x8*)(C + (size_t)sa * 256 + li * 8);
    f16x8 vb = *(const f16x8*)(C + (size_t)sb * 256 + li * 8);
    a0 += wa * (float)va[0] + wb * (float)vb[0];
    a1 += wa * (float)va[1] + wb * (float)vb[1];
    a2 += wa * (float)va[2] + wb * (float)vb[2];
    a3 += wa * (float)va[3] + wb * (float)vb[3];
    a4 += wa * (float)va[4] + wb * (float)vb[4];
    a5 += wa * (float)va[5] + wb * (float)vb[5];
    a6 += wa * (float)va[6] + wb * (float)vb[6];
    a7 += wa * (float)va[7] + wb * (float)vb[7];
    e += 4;
  }
  if (e + 2 <= end) {
    int sa = csr_src[e + sel];
    float wa = csr_coef[e + sel];
    f16x8 va = *(const f16x8*)(C + (size_t)sa * 256 + li * 8);
    a0 += wa * (float)va[0]; a1 += wa * (float)va[1];
    a2 += wa * (float)va[2]; a3 += wa * (float)va[3];
    a4 += wa * (float)va[4]; a5 += wa * (float)va[5];
    a6 += wa * (float)va[6]; a7 += wa * (float)va[7];
    e += 2;
  }
  if (e < end) {  // odd tail: lower half only (upper half weight 0)
    int sa = csr_src[e];
    float wa = (sel == 0) ? csr_coef[e] : 0.f;
    f16x8 va = *(const f16x8*)(C + (size_t)sa * 256 + li * 8);
    a0 += wa * (float)va[0]; a1 += wa * (float)va[1];
    a2 += wa * (float)va[2]; a3 += wa * (float)va[3];
    a4 += wa * (float)va[4]; a5 += wa * (float)va[5];
    a6 += wa * (float)va[6]; a7 += wa * (float)va[7];
  }
  // combine even/odd halves
  a0 += __shfl_xor(a0, 32); a1 += __shfl_xor(a1, 32);
  a2 += __shfl_xor(a2, 32); a3 += __shfl_xor(a3, 32);
  a4 += __shfl_xor(a4, 32); a5 += __shfl_xor(a5, 32);
  a6 += __shfl_xor(a6, 32); a7 += __shfl_xor(a7, 32);
  // self + scale + bias + ELU (all lanes compute; lanes 0-31 write 16B each)
  const float dd = dinv[n];
  f16x8 sv = *(const f16x8*)(C + (size_t)n * 256 + li * 8);
  float4 b0 = ((const float4*)bias)[li * 2];
  float4 b1 = ((const float4*)bias)[li * 2 + 1];
  float r0 = dd * (a0 + (float)sv[0]) + b0.x;
  float r1 = dd * (a1 + (float)sv[1]) + b0.y;
  float r2 = dd * (a2 + (float)sv[2]) + b0.z;
  float r3 = dd * (a3 + (float)sv[3]) + b0.w;
  float r4 = dd * (a4 + (float)sv[4]) + b1.x;
  float r5 = dd * (a5 + (float)sv[5]) + b1.y;
  float r6 = dd * (a6 + (float)sv[6]) + b1.z;
  float r7 = dd * (a7 + (float)sv[7]) + b1.w;
  r0 = (r0 > 0.f) ? r0 : expm1f(r0);
  r1 = (r1 > 0.f) ? r1 : expm1f(r1);
  r2 = (r2 > 0.f) ? r2 : expm1f(r2);
  r3 = (r3 > 0.f) ? r3 : expm1f(r3);
  r4 = (r4 > 0.f) ? r4 : expm1f(r4);
  r5 = (r5 > 0.f) ? r5 : expm1f(r5);
  r6 = (r6 > 0.f) ? r6 : expm1f(r6);
  r7 = (r7 > 0.f) ? r7 : expm1f(r7);
  if (sel == 0) {
    f16x8 o;
    o[0] = (f16)r0; o[1] = (f16)r1; o[2] = (f16)r2; o[3] = (f16)r3;
    o[4] = (f16)r4; o[5] = (f16)r5; o[6] = (f16)r6; o[7] = (f16)r7;
    *(f16x8*)(O + (size_t)n * 256 + li * 8) = o;
  }
}

// ---------------- pooling (sorted batch -> ranges) + final linear -------------
__global__ __launch_bounds__(256) void find_start(const int* __restrict__ batch,
                                                  int* __restrict__ gstart) {
  int g = blockIdx.x * 256 + threadIdx.x;
  if (g <= NUM_GRAPHS) {
    int lo = 0, hi = N_NODES;
    while (lo < hi) {
      int mid = (lo + hi) >> 1;
      if (batch[mid] < g) lo = mid + 1; else hi = mid;
    }
    gstart[g] = lo;
  }
}

__global__ __launch_bounds__(256) void pool_final(
    const f16* __restrict__ H, const int* __restrict__ gstart,
    const float* __restrict__ W, const float* __restrict__ b,
    float* __restrict__ out) {
  int g = blockIdx.x;
  __shared__ float part[NCLS * 256];
  int f = threadIdx.x;
  int s = gstart[g], e = gstart[g + 1];
  float sum = 0.f;
  for (int n = s; n < e; ++n) sum += (float)H[(size_t)n * HID + f];
  float v = sum / fmaxf((float)(e - s), 1.0f);
#pragma unroll
  for (int c = 0; c < NCLS; ++c) part[c * 256 + f] = v * W[f * NCLS + c];
  __syncthreads();
  for (int off = 128; off > 0; off >>= 1) {
    if (f < off) {
#pragma unroll
      for (int c = 0; c < NCLS; ++c) part[c * 256 + f] += part[c * 256 + f + off];
    }
    __syncthreads();
  }
  if (f < NCLS) out[g * NCLS + f] = part[f * 256] + b[f];
}

extern "C" void kernel_launch(void* const* d_in, const int* in_sizes, int n_in,
                              void* d_out, int out_size, void* d_ws, size_t ws_size,
                              hipStream_t stream) {
  const float* x = (const float*)d_in[0];
  const int* ei = (const int*)d_in[1];
  const int* e_src = ei;
  const int* e_dst = ei + N_EDGES;
  const float* ea = (const float*)d_in[2];
  const int* batch = (const int*)d_in[4];
  const float* enc1_w = (const float*)d_in[5];
  const float* enc1_b = (const float*)d_in[6];
  const float* enc2_w = (const float*)d_in[7];
  const float* enc2_b = (const float*)d_in[8];
  const float* conv_ws = (const float*)d_in[9];
  const float* conv_bs = (const float*)d_in[10];
  const float* lin1_w = (const float*)d_in[11];
  const float* lin1_b = (const float*)d_in[12];
  float* out = (float*)d_out;

  char* w = (char*)d_ws;
  size_t off = 0;
  auto alloc = [&](size_t bytes) {
    size_t o = off;
    off = (off + bytes + 255) & ~(size_t)255;
    return (void*)(w + o);
  };
  const size_t PLANE = (size_t)N_NODES * HID;
  f16* Ahp = (f16*)alloc(PLANE * 2);   // conv GEMM out (dinv-scaled hW)
  f16* Bhp = (f16*)alloc(PLANE * 2);   // activations h
  const size_t WTOT = 32768 + 4 * 65536;
  f16* wth = (f16*)alloc(WTOT * 2);
  f16* wtl = (f16*)alloc(WTOT * 2);
  float* wc_f32 = (float*)alloc((size_t)F_IN * HID * 4);
  float* bc = (float*)alloc((size_t)HID * 4);
  unsigned long long* dpack = (unsigned long long*)alloc((size_t)N_NODES * 8);
  float* dinv = (float*)alloc((size_t)N_NODES * 4);
  int* row_ptr = (int*)alloc((size_t)(N_NODES + 1) * 4);
  int* tmp_pos = (int*)alloc((size_t)N_EDGES * 4);
  int* bsum = (int*)alloc((size_t)256 * 4);
  int* csr_src = (int*)alloc((size_t)N_EDGES * 4);
  float* csr_coef = (float*)alloc((size_t)N_EDGES * 4);
  int* gstart = (int*)alloc((size_t)(NUM_GRAPHS + 1) * 4);
  (void)ws_size; (void)in_sizes; (void)n_in; (void)out_size;

  hipMemsetAsync(dpack, 0, (size_t)N_NODES * 8, stream);

  const int nb_nodes = (N_NODES + 255) / 256;
  const int nb_edges = (N_EDGES + 255) / 256;

  // graph normalization + CSR (feature-independent)
  deg_pos<<<nb_edges, 256, 0, stream>>>(e_dst, ea, dpack, tmp_pos, N_EDGES);
  scan_p1<<<nb_nodes, 256, 0, stream>>>(dpack, dinv, bsum, N_NODES);
  scan_p2<<<1, 256, 0, stream>>>(bsum, nb_nodes, row_ptr + N_NODES);
  scan_p3<<<nb_nodes, 256, 0, stream>>>(dpack, bsum, row_ptr, N_NODES);
  csr_fill<<<nb_edges, 256, 0, stream>>>(e_src, e_dst, ea, row_ptr, tmp_pos,
                                         csr_src, csr_coef, N_EDGES);
  find_start<<<(NUM_GRAPHS + 256) / 256, 256, 0, stream>>>(batch, gstart);

  // combined encoder: Wc = W1@W2 (fp32), bc = b1@W2 + b2
  wc_gemm<<<(F_IN * HID + 255) / 256, 256, 0, stream>>>(enc1_w, enc2_w, wc_f32);
  bc_gemv<<<1, 256, 0, stream>>>(enc1_b, enc2_w, enc2_b, bc);

  // x -> f16 (into A plane; dead after encoder GEMM)
  f16* xh = Ahp;
  {
    int n4 = N_NODES * F_IN / 4;
    split_hi<<<(n4 + 255) / 256, 256, 0, stream>>>(x, xh, n4);
  }
  // weight transpose+split (hi+lo): combined encoder (K=128,Mc=256) + convs
  f16* ech = wth;            f16* ecl = wtl;
  f16* cvh = wth + 32768;    f16* cvl = wtl + 32768;
  tsplit<<<(32768 + 255) / 256, 256, 0, stream>>>(wc_f32, ech, ecl, F_IN, HID, 32768);
  tsplit<<<(262144 + 255) / 256, 256, 0, stream>>>(conv_ws, cvh, cvl, HID, HID, 262144);

  const int gR = (N_NODES + 127) / 128;  // 391

  // fused encoder: h = x@Wc + bc -> B plane
  {
    dim3 grid(gR, 2);
    gemm_mfma<<<grid, 256, 0, stream>>>(xh, ech, ecl, bc, nullptr, Bhp,
                                        N_NODES, F_IN, HID);
  }

  // 4 GCN layers: C = dinv*(h@W) (B->A); aggregate+bias+ELU (A->B)
  for (int layer = 0; layer < 4; ++layer) {
    dim3 grid(gR, 2);
    gemm_mfma<<<grid, 256, 0, stream>>>(Bhp,
                                        cvh + (size_t)layer * 65536,
                                        cvl + (size_t)layer * 65536,
                                        nullptr, dinv, Ahp, N_NODES, HID, HID);
    gather_elu<<<(N_NODES + 3) / 4, 256, 0, stream>>>(
        Ahp, dinv, row_ptr, csr_src, csr_coef,
        conv_bs + (size_t)layer * HID, Bhp);
  }

  // deterministic mean-pool per graph + final linear (fused)
  pool_final<<<NUM_GRAPHS, 256, 0, stream>>>(Bhp, gstart, lin1_w, lin1_b, out);
}